// Round 7
// baseline (263.321 us; speedup 1.0000x reference)
//
#include <hip/hip_runtime.h>
#include <hip/hip_bf16.h>

#define FEAT 128
#define HID  256
#define ACTD 32

typedef __attribute__((ext_vector_type(8))) short bf16x8;
typedef __attribute__((ext_vector_type(4))) float f32x4;
typedef __attribute__((ext_vector_type(2))) float f32x2;

__device__ __forceinline__ ushort f2b(float f) {
    __hip_bfloat16 h = __float2bfloat16(f);
    return *(ushort*)&h;
}
__device__ __forceinline__ uint pack2(float lo, float hi) {
    return (uint)f2b(lo) | ((uint)f2b(hi) << 16);
}
// fp8 e4m3 helpers (hardware cvt; OCP on gfx950)
__device__ __forceinline__ f32x2 upk_lo(uint u) { return __builtin_amdgcn_cvt_pk_f32_fp8(u, false); }
__device__ __forceinline__ f32x2 upk_hi(uint u) { return __builtin_amdgcn_cvt_pk_f32_fp8(u, true); }

__device__ __forceinline__ void add8(float* acc, uint2 g) {
    f32x2 l0 = upk_lo(g.x), h0 = upk_hi(g.x);
    f32x2 l1 = upk_lo(g.y), h1 = upk_hi(g.y);
    acc[0] += l0[0]; acc[1] += l0[1]; acc[2] += h0[0]; acc[3] += h0[1];
    acc[4] += l1[0]; acc[5] += l1[1]; acc[6] += h1[0]; acc[7] += h1[1];
}

// ---------------------------------------------------------------------------
// Graph preprocessing (separate launches: HW launch gaps are far cheaper than
// software grid barriers on MI355X -- R5 measured spin-barrier preproc at
// 360us from cross-XCD atomic line ping-pong)
// ---------------------------------------------------------------------------

// merged histogram + per-graph bounds
__global__ void hist_bounds(const int* __restrict__ dst, int* __restrict__ cnt, int E,
                            const int* __restrict__ batch, int* __restrict__ sg,
                            int* __restrict__ eg, int n) {
    int i = blockIdx.x * blockDim.x + threadIdx.x;
    if (i < E) atomicAdd(&cnt[dst[i]], 1);
    if (i < n) {
        int b = batch[i];
        if (i == 0 || batch[i - 1] != b) sg[b] = i;
        if (i == n - 1 || batch[i + 1] != b) eg[b] = i + 1;
    }
}

// single-launch scan: block-local LDS scan + atomic ticket for block base.
// CSR segments need not be vertex-ordered -- any disjoint allocation works
// (fill uses per-row cursors; agg reads [row_ptr, row_end)). Ticket = cnt[n]
// (zeroed by the cnt memset).
__global__ __launch_bounds__(256) void scan_one(const int* __restrict__ cnt,
        int* __restrict__ row_ptr, int* __restrict__ row_end,
        int* __restrict__ fill_pos, float* __restrict__ dis,
        int* __restrict__ ticket, int n) {
    __shared__ int s[256];
    __shared__ int base_sh;
    int t = threadIdx.x;
    int i = blockIdx.x * 256 + t;
    int c = (i < n) ? cnt[i] : 0;
    s[t] = c;
    __syncthreads();
    for (int off = 1; off < 256; off <<= 1) {
        int u = (t >= off) ? s[t - off] : 0;
        __syncthreads();
        s[t] += u;
        __syncthreads();
    }
    if (t == 255) base_sh = atomicAdd(ticket, s[255]);
    __syncthreads();
    if (i < n) {
        int ex = base_sh + s[t] - c;
        row_ptr[i] = ex;
        row_end[i] = ex + c;
        fill_pos[i] = ex;
        dis[i] = rsqrtf((float)c + 1.0f);   // +1 self-loop
    }
}

// merged fill + elementwise prep (one launch; both depend only on scan_one):
//   part 0: col_idx fill via per-row atomic cursors      (E items)
//   part 1: xs[v][f] = fp8(8 * x[v][f] * dis[v])         (n*32 uint items)
//   part 2: WT1 bf16 [512][128]   <- q1_W1,q2_W1 (transposed)
//   part 3: WT2f fp8 [2][256][256] <- 8 * q{1,2}_W2 (transposed)
__global__ void fill_prep(const int* __restrict__ src, const int* __restrict__ dst,
                          int* __restrict__ fill_pos, int* __restrict__ col_idx, int E,
                          const float* __restrict__ x, const float* __restrict__ dis,
                          uchar* __restrict__ xs,
                          const float* __restrict__ W1a, const float* __restrict__ W1b,
                          const float* __restrict__ W2a, const float* __restrict__ W2b,
                          ushort* __restrict__ WT1, uchar* __restrict__ WT2f, int n) {
    int i = blockIdx.x * blockDim.x + threadIdx.x;
    if (i < E) {
        int d = dst[i];
        int pos = atomicAdd(&fill_pos[d], 1);
        col_idx[pos] = src[i];
        return;
    }
    i -= E;
    const int nscale = n * (FEAT / 4);
    if (i < nscale) {
        int v = i >> 5;
        float dv = dis[v] * 8.f;
        float4 f = ((const float4*)x)[i];
        uint p = __builtin_amdgcn_cvt_pk_fp8_f32(f.x * dv, f.y * dv, 0, false);
        p = __builtin_amdgcn_cvt_pk_fp8_f32(f.z * dv, f.w * dv, p, true);
        ((uint*)xs)[i] = p;
        return;
    }
    i -= nscale;
    if (i < 2 * FEAT * HID) {
        int head = i >> 15;                  // /(128*256)
        int rem = i & 32767;
        int k = rem >> 8, nn = rem & 255;    // W1 [128][256]
        const float* W = head ? W1b : W1a;
        WT1[(size_t)(head * 256 + nn) * FEAT + k] = f2b(W[rem]);
    } else {
        int j = i - 2 * FEAT * HID;
        if (j >= 2 * HID * HID) return;
        int head = j >> 16;                  // /(256*256)
        int rem = j & 65535;
        int k = rem >> 8, nn = rem & 255;    // W2 [256][256]
        const float* W = head ? W2b : W2a;
        float v = W[rem] * 8.f;
        uint q = __builtin_amdgcn_cvt_pk_fp8_f32(v, v, 0, false);
        WT2f[(size_t)head * 65536 + nn * 256 + k] = (uchar)(q & 0xff);
    }
}

// ---------------------------------------------------------------------------
// agg128: z[v] = bf16((dis[v]/8) * (xs[v] + sum_{s in N(v)} xs[s]))  (fp8 in)
// 4-edges-per-load restructure: 4 sub-groups of 16 lanes; each lane loads
// uint2 (8 fp8 feats), 16 lanes/row -> one load instr gathers 4 edges.
// xs is L2/L3-resident (6.4 MB) so this kernel is issue-bound, not BW-bound:
// 4x fewer gather instrs + 32 edges in flight per batch.
// ---------------------------------------------------------------------------

__global__ __launch_bounds__(256) void agg128(
        const uchar* __restrict__ xs, const float* __restrict__ dis,
        const int* __restrict__ row_ptr, const int* __restrict__ row_end,
        const int* __restrict__ col_idx,
        ushort* __restrict__ z, int n) {
    const int wave = threadIdx.x >> 6, lane = threadIdx.x & 63;
    const int v = blockIdx.x * 4 + wave;
    if (v >= n) return;
    const int sub = lane >> 4, fl = lane & 15;   // sub-group, feature slot
    const uint2* X8 = (const uint2*)xs;          // 16 uint2 per 128B row
    float acc[8] = {};
    if (sub == 0) add8(acc, X8[(size_t)v * 16 + fl]);   // self-loop
    const int e0 = row_ptr[v], e1 = row_end[v];
    for (int e = e0; e < e1; e += 32) {
        uint2 m[8];
#pragma unroll
        for (int j = 0; j < 8; ++j) {
            int edge = e + 4 * j + sub;
            uint2 g = {0u, 0u};                  // fp8 0x00 unpacks to 0.0f
            if (edge < e1) g = X8[(size_t)col_idx[edge] * 16 + fl];
            m[j] = g;
        }
#pragma unroll
        for (int j = 0; j < 8; ++j) add8(acc, m[j]);
    }
    // combine the 4 sub-group partials
#pragma unroll
    for (int i = 0; i < 8; ++i) {
        acc[i] += __shfl_xor(acc[i], 16, 64);
        acc[i] += __shfl_xor(acc[i], 32, 64);
    }
    if (sub == 0) {
        float sc = dis[v] * 0.125f;
        uint4 q;
        q.x = pack2(acc[0] * sc, acc[1] * sc);
        q.y = pack2(acc[2] * sc, acc[3] * sc);
        q.z = pack2(acc[4] * sc, acc[5] * sc);
        q.w = pack2(acc[6] * sc, acc[7] * sc);
        ((uint4*)z)[(size_t)v * 16 + fl] = q;    // 16 lanes x 16B = 256B row
    }
}

// ---------------------------------------------------------------------------
// agg512: z2f[v][j] = fp8( (dis[v]/4) * (h1[v][j] + sum_{s} h1[s][j]) )  (fp8 in/out)
// simple unroll-8 (best measured; manual pipelining regressed; fabric-bound)
// ---------------------------------------------------------------------------

__global__ __launch_bounds__(256) void agg512(
        const uchar* __restrict__ h1, const float* __restrict__ dis,
        const int* __restrict__ row_ptr, const int* __restrict__ row_end,
        const int* __restrict__ col_idx,
        uchar* __restrict__ z2f, int n) {
    const int wave = threadIdx.x >> 6, lane = threadIdx.x & 63;
    const int v = blockIdx.x * 4 + wave;
    if (v >= n) return;
    const uint2* H = (const uint2*)h1;
    float acc[8];
    {
        uint2 g = H[(size_t)v * 64 + lane];
        f32x2 l0 = upk_lo(g.x), h0 = upk_hi(g.x);
        f32x2 l1 = upk_lo(g.y), h1v = upk_hi(g.y);
        acc[0] = l0[0]; acc[1] = l0[1]; acc[2] = h0[0]; acc[3] = h0[1];
        acc[4] = l1[0]; acc[5] = l1[1]; acc[6] = h1v[0]; acc[7] = h1v[1];
    }
    const int e0 = row_ptr[v], e1 = row_end[v];
    int e = e0;
    for (; e + 8 <= e1; e += 8) {
        uint2 m[8];
#pragma unroll
        for (int j = 0; j < 8; ++j) m[j] = H[(size_t)col_idx[e + j] * 64 + lane];
#pragma unroll
        for (int j = 0; j < 8; ++j) add8(acc, m[j]);
    }
    for (; e < e1; ++e) add8(acc, H[(size_t)col_idx[e] * 64 + lane]);
    float sc = dis[v] * 0.25f;
    uint lo = __builtin_amdgcn_cvt_pk_fp8_f32(acc[0] * sc, acc[1] * sc, 0, false);
    lo = __builtin_amdgcn_cvt_pk_fp8_f32(acc[2] * sc, acc[3] * sc, lo, true);
    uint hi = __builtin_amdgcn_cvt_pk_fp8_f32(acc[4] * sc, acc[5] * sc, 0, false);
    hi = __builtin_amdgcn_cvt_pk_fp8_f32(acc[6] * sc, acc[7] * sc, hi, true);
    uint2 o = {lo, hi};
    ((uint2*)z2f)[(size_t)v * 64 + lane] = o;
}

// ---------------------------------------------------------------------------
// GEMM1: h1[m][head*256+nl] = fp8( 16*dis[m]*relu(z[m].WT1[head*256+nl] + b1[nl]) )
// BM=128, 512 threads (4 row-waves x 2 col-waves; wave tile 32x128), K=128.
// B panel (64 KB bf16) staged in LDS; A read direct global->reg.
// MFMA operands SWAPPED (compute C^T) so each lane holds 4 consecutive n
// values -> fp8 output packed to dword stores (4x fewer, 4x better coalesce).
// ---------------------------------------------------------------------------

__global__ __launch_bounds__(512) void gemm1_mfma(
        const ushort* __restrict__ z,           // bf16 [M][128]
        const ushort* __restrict__ WT1,         // bf16 [512][128]
        const float* __restrict__ b1a, const float* __restrict__ b1b,
        const float* __restrict__ dis,
        uchar* __restrict__ out, int M) {       // h1 fp8 [M][512]
    constexpr int K = FEAT;                     // 128
    __shared__ char Bs[256 * 256];              // 64 KB bf16 B panel (swizzled)
    const int tid = threadIdx.x;
    const int bm = blockIdx.x * 128;
    const int head = blockIdx.y;
    const ushort* WT = WT1 + (size_t)head * 256 * K;
    const float* bias = head ? b1b : b1a;

    // stage B: 256 rows (n) x 16 segs of 16B, swizzled
    for (int idx = tid; idx < 256 * 16; idx += 512) {
        int nr = idx >> 4, seg = idx & 15;
        int4 val = *(const int4*)(WT + (size_t)nr * K + seg * 8);
        int byte = (nr * 256 + seg * 16) ^ ((nr & 7) << 4);
        *(int4*)(Bs + byte) = val;
    }
    __syncthreads();

    const int warp = tid >> 6, lane = tid & 63;
    const int wr = warp >> 1, wc = warp & 1;    // 4 row-waves x 2 col-waves
    const int kgrp = lane >> 4;
    const int r0 = wr * 32 + (lane & 15);       // + m*16 (block-local row, A side)
    const int c0 = wc * 128 + (lane & 15);      // + nf*16 (block-local col, B side)

    f32x4 acc[2][8] = {};
    const bf16x8 zv = {};
    for (int ks = 0; ks < 4; ++ks) {
        bf16x8 a[2], b[8];
#pragma unroll
        for (int m = 0; m < 2; ++m) {
            int grow = bm + r0 + m * 16;
            a[m] = (grow < M)
                 ? *(const bf16x8*)(z + (size_t)grow * K + ks * 32 + kgrp * 8)
                 : zv;
        }
#pragma unroll
        for (int nf = 0; nf < 8; ++nf) {
            int nr = c0 + nf * 16;
            int byte = (nr * 256 + ks * 64 + kgrp * 16) ^ ((nr & 7) << 4);
            b[nf] = *(const bf16x8*)(Bs + byte);
        }
        // swapped operands: D = C^T, so row-dim = n, col-dim = m
#pragma unroll
        for (int nf = 0; nf < 8; ++nf)
#pragma unroll
            for (int m = 0; m < 2; ++m)
                acc[m][nf] = __builtin_amdgcn_mfma_f32_16x16x32_bf16(b[nf], a[m], acc[m][nf], 0, 0, 0);
    }

    // epilogue: lane&15 -> m-row, (lane>>4)*4 + reg -> n  => pack 4 fp8 / dword
    const int ml = lane & 15;
    const int ngrp = (lane >> 4) * 4;
#pragma unroll
    for (int m = 0; m < 2; ++m) {
        int grow = bm + wr * 32 + m * 16 + ml;
        if (grow >= M) continue;
        float d = dis[grow] * 16.f;
#pragma unroll
        for (int nf = 0; nf < 8; ++nf) {
            int n0 = wc * 128 + nf * 16 + ngrp;
            float4 bv = *(const float4*)(bias + n0);
            f32x4 ac = acc[m][nf];
            float v0 = fmaxf(ac[0] + bv.x, 0.f) * d;
            float v1 = fmaxf(ac[1] + bv.y, 0.f) * d;
            float v2 = fmaxf(ac[2] + bv.z, 0.f) * d;
            float v3 = fmaxf(ac[3] + bv.w, 0.f) * d;
            uint q = __builtin_amdgcn_cvt_pk_fp8_f32(v0, v1, 0, false);
            q = __builtin_amdgcn_cvt_pk_fp8_f32(v2, v3, q, true);
            *(uint*)(out + (size_t)grow * 512 + head * 256 + n0) = q;
        }
    }
}

// ---------------------------------------------------------------------------
// GEMM2 (fp8 x fp8 MFMA) + fused mean-pool via shuffle reduction.
// BM=128, 512 threads (4 row-waves x 2 col-waves; wave tile 32x128), K=256.
// ---------------------------------------------------------------------------

__global__ __launch_bounds__(512) void gemm2_pool(
        const uchar* __restrict__ z2f,          // fp8 [M][512]
        const uchar* __restrict__ WT2f,         // fp8 [2][256][256]
        const float* __restrict__ b2a, const float* __restrict__ b2b,
        const int* __restrict__ batch,
        float* __restrict__ pooled, int M) {    // pooled [G][512]
    constexpr int K = HID;                      // 256
    __shared__ char Bs[256 * 256];              // 64 KB fp8 B panel (swizzled)
    __shared__ int rows_g[128];
    const int tid = threadIdx.x;
    const int bm = blockIdx.x * 128;
    const int head = blockIdx.y;
    const uchar* WT = WT2f + (size_t)head * 65536;
    const float* bias = head ? b2b : b2a;

    // stage B: 256 rows x 32 segs of 8B, swizzled at 8B granularity
    for (int idx = tid; idx < 256 * 32; idx += 512) {
        int nr = idx >> 5, seg = idx & 31;
        uint2 val = *(const uint2*)(WT + (size_t)nr * 256 + seg * 8);
        int byte = (nr * 256 + seg * 8) ^ ((nr & 7) << 3);
        *(uint2*)(Bs + byte) = val;
    }
    if (tid < 128) rows_g[tid] = batch[min(bm + tid, M - 1)];
    __syncthreads();

    const int warp = tid >> 6, lane = tid & 63;
    const int wr = warp >> 1, wc = warp & 1;    // 4 row-waves x 2 col-waves
    const int kgrp = lane >> 4;
    const int r0 = wr * 32 + (lane & 15);       // + m*16 (block-local row)
    const int c0 = wc * 128 + (lane & 15);      // + nf*16 (block-local col)
    const uchar* Abase = z2f + (size_t)head * 256;

    f32x4 acc[2][8] = {};
    for (int ks = 0; ks < 8; ++ks) {
        long a[2], b[8];
#pragma unroll
        for (int m = 0; m < 2; ++m) {
            int grow = bm + r0 + m * 16;
            a[m] = (grow < M)
                 ? *(const long*)(Abase + (size_t)grow * 512 + ks * 32 + kgrp * 8)
                 : 0L;
        }
#pragma unroll
        for (int nf = 0; nf < 8; ++nf) {
            int nr = c0 + nf * 16;
            int byte = (nr * 256 + ks * 32 + kgrp * 8) ^ ((nr & 7) << 3);
            b[nf] = *(const long*)(Bs + byte);
        }
#pragma unroll
        for (int nf = 0; nf < 8; ++nf)
#pragma unroll
            for (int m = 0; m < 2; ++m)
                acc[m][nf] = __builtin_amdgcn_mfma_f32_16x16x32_fp8_fp8(a[m], b[nf], acc[m][nf], 0, 0, 0);
    }

    // ---- fused pooling epilogue (wave's 32-row window spans <=2 graphs) ----
    const int rbw = wr * 32;
    const int g0 = rows_g[rbw];
    const int glast = rows_g[min(127, rbw + 31)];
    float s0[8] = {}, s1[8] = {};
#pragma unroll
    for (int m = 0; m < 2; ++m) {
#pragma unroll
        for (int r = 0; r < 4; ++r) {
            int lrow = rbw + m * 16 + (lane >> 4) * 4 + r;
            int grow = bm + lrow;
            if (grow < M) {
                bool in0 = (rows_g[lrow] == g0);
#pragma unroll
                for (int nf = 0; nf < 8; ++nf) {
                    float val = fmaxf(acc[m][nf][r] * 0.03125f + bias[c0 + nf * 16], 0.f);
                    if (in0) s0[nf] += val; else s1[nf] += val;
                }
            }
        }
    }
#pragma unroll
    for (int nf = 0; nf < 8; ++nf) {
        s0[nf] += __shfl_xor(s0[nf], 16, 64);
        s0[nf] += __shfl_xor(s0[nf], 32, 64);
        s1[nf] += __shfl_xor(s1[nf], 16, 64);
        s1[nf] += __shfl_xor(s1[nf], 32, 64);
    }
    if (kgrp == 0) {
#pragma unroll
        for (int nf = 0; nf < 8; ++nf) {
            int n = head * 256 + c0 + nf * 16;
            atomicAdd(&pooled[(size_t)g0 * 512 + n], s0[nf]);
            if (glast != g0) atomicAdd(&pooled[(size_t)glast * 512 + n], s1[nf]);
        }
    }
}

// final dot: 512 threads, head = t>>8, feature f = t&255
__global__ __launch_bounds__(512) void final_dot(
        const float* __restrict__ pooled, const int* __restrict__ sg,
        const int* __restrict__ eg, const float* __restrict__ action,
        const float* __restrict__ fcW1, const float* __restrict__ fcb1,
        const float* __restrict__ fcW2, const float* __restrict__ fcb2,
        float* __restrict__ out, int G) {
    int g = blockIdx.x, t = threadIdx.x;
    int head = t >> 8, f = t & 255;
    const float* fcW = head ? fcW2 : fcW1;
    float inv = 1.f / (float)(eg[g] - sg[g]);
    float p = pooled[g * 512 + t] * inv * fcW[f];
    if (f < ACTD) p += action[g * ACTD + f] * fcW[HID + f];
    for (int off = 32; off; off >>= 1) p += __shfl_down(p, off, 64);
    __shared__ float red[8];
    if ((t & 63) == 0) red[t >> 6] = p;
    __syncthreads();
    if (t == 0)   out[g]     = red[0] + red[1] + red[2] + red[3] + fcb1[0];
    if (t == 256) out[G + g] = red[4] + red[5] + red[6] + red[7] + fcb2[0];
}

// ---------------------------------------------------------------------------

extern "C" void kernel_launch(void* const* d_in, const int* in_sizes, int n_in,
                              void* d_out, int out_size, void* d_ws, size_t ws_size,
                              hipStream_t stream) {
    const float* x      = (const float*)d_in[0];
    const int*   ei     = (const int*)d_in[1];
    const int*   batch  = (const int*)d_in[2];
    const float* action = (const float*)d_in[3];
    const float* q1_W1  = (const float*)d_in[4];
    const float* q1_b1  = (const float*)d_in[5];
    const float* q1_W2  = (const float*)d_in[6];
    const float* q1_b2  = (const float*)d_in[7];
    const float* q1_fcW = (const float*)d_in[8];
    const float* q1_fcb = (const float*)d_in[9];
    const float* q2_W1  = (const float*)d_in[10];
    const float* q2_b1  = (const float*)d_in[11];
    const float* q2_W2  = (const float*)d_in[12];
    const float* q2_b2  = (const float*)d_in[13];
    const float* q2_fcW = (const float*)d_in[14];
    const float* q2_fcb = (const float*)d_in[15];

    const int N = in_sizes[2];
    const int E = in_sizes[1] / 2;
    const int G = in_sizes[3] / ACTD;
    const int* src = ei;
    const int* dst = ei + E;

    char* w = (char*)d_ws;
    size_t off = 0;
    auto take = [&](size_t bytes) -> void* {
        void* p = w + off;
        off = (off + bytes + 255) & ~(size_t)255;
        return p;
    };
    // cnt block: cnt[0..N-1], ticket=cnt[N]; pooled allocated immediately
    // after -> ONE memset zeroes both.
    int*    cnt      = (int*)take((size_t)(N + 1) * 4);
    float*  pooled   = (float*)take((size_t)G * 512 * 4);
    int*    row_ptr  = (int*)take((size_t)N * 4);
    int*    row_end  = (int*)take((size_t)N * 4);
    int*    fill_pos = (int*)take((size_t)N * 4);
    float*  dis      = (float*)take((size_t)N * 4);
    int*    col_idx  = (int*)take((size_t)E * 4);
    int*    sg       = (int*)take((size_t)G * 4);
    int*    eg       = (int*)take((size_t)G * 4);
    ushort* WT1      = (ushort*)take((size_t)512 * FEAT * 2);    // bf16 [512][128]
    uchar*  WT2f     = (uchar*)take((size_t)2 * HID * HID);      // fp8 [2][256][256]
    uchar*  xs       = (uchar*)take((size_t)N * FEAT);           // fp8
    ushort* z        = (ushort*)take((size_t)N * FEAT * 2);      // bf16
    uchar*  h1       = (uchar*)take((size_t)N * 512);            // fp8
    uchar*  z2f      = (uchar*)take((size_t)N * 512);            // fp8
    (void)ws_size;

    const int TB = 256;
    const int nb = (N + 255) / 256;
    size_t zlen = (size_t)((char*)pooled - (char*)cnt) + (size_t)G * 512 * 4;
    hipMemsetAsync(cnt, 0, zlen, stream);

    int hb_grid = (max(E, N) + TB - 1) / TB;
    hist_bounds<<<hb_grid, TB, 0, stream>>>(dst, cnt, E, batch, sg, eg, N);
    scan_one<<<nb, TB, 0, stream>>>(cnt, row_ptr, row_end, fill_pos, dis, cnt + N, N);

    int fptotal = E + N * (FEAT / 4) + 2 * FEAT * HID + 2 * HID * HID;
    fill_prep<<<(fptotal + TB - 1) / TB, TB, 0, stream>>>(
        src, dst, fill_pos, col_idx, E,
        x, dis, xs, q1_W1, q2_W1, q1_W2, q2_W2, WT1, WT2f, N);

    int agg_grid = (N + 3) / 4;
    int gx128 = (N + 127) / 128;

    agg128<<<agg_grid, TB, 0, stream>>>(xs, dis, row_ptr, row_end, col_idx, z, N);
    gemm1_mfma<<<dim3(gx128, 2), 512, 0, stream>>>(z, WT1, q1_b1, q2_b1, dis, h1, N);
    agg512<<<agg_grid, TB, 0, stream>>>(h1, dis, row_ptr, row_end, col_idx, z2f, N);
    gemm2_pool<<<dim3(gx128, 2), 512, 0, stream>>>(z2f, WT2f, q1_b2, q2_b2, batch,
                                                   pooled, N);
    final_dot<<<G, 512, 0, stream>>>(pooled, sg, eg, action,
                                     q1_fcW, q1_fcb, q2_fcW, q2_fcb,
                                     (float*)d_out, G);
}

// Round 8
// 234.870 us; speedup vs baseline: 1.1211x; 1.1211x over previous
//
#include <hip/hip_runtime.h>
#include <hip/hip_bf16.h>

#define FEAT 128
#define HID  256
#define ACTD 32

typedef __attribute__((ext_vector_type(8))) short bf16x8;
typedef __attribute__((ext_vector_type(4))) float f32x4;
typedef __attribute__((ext_vector_type(2))) float f32x2;

__device__ __forceinline__ ushort f2b(float f) {
    __hip_bfloat16 h = __float2bfloat16(f);
    return *(ushort*)&h;
}
__device__ __forceinline__ uint pack2(float lo, float hi) {
    return (uint)f2b(lo) | ((uint)f2b(hi) << 16);
}
// fp8 e4m3 helpers (hardware cvt; OCP on gfx950)
__device__ __forceinline__ f32x2 upk_lo(uint u) { return __builtin_amdgcn_cvt_pk_f32_fp8(u, false); }
__device__ __forceinline__ f32x2 upk_hi(uint u) { return __builtin_amdgcn_cvt_pk_f32_fp8(u, true); }

__device__ __forceinline__ void add8(float* acc, uint2 g) {
    f32x2 l0 = upk_lo(g.x), h0 = upk_hi(g.x);
    f32x2 l1 = upk_lo(g.y), h1 = upk_hi(g.y);
    acc[0] += l0[0]; acc[1] += l0[1]; acc[2] += h0[0]; acc[3] += h0[1];
    acc[4] += l1[0]; acc[5] += l1[1]; acc[6] += h1[0]; acc[7] += h1[1];
}

// ---------------------------------------------------------------------------
// Graph preprocessing (separate launches: HW launch gaps are far cheaper than
// software grid barriers on MI355X -- R5 measured spin-barrier preproc at
// 360us from cross-XCD atomic line ping-pong)
// ---------------------------------------------------------------------------

// merged histogram + per-graph bounds. The atomic's return value IS the
// edge's rank within its destination row -> store it so the fill pass needs
// no atomics at all (R8 rank trick).
__global__ void hist_bounds(const int* __restrict__ dst, int* __restrict__ cnt, int E,
                            const int* __restrict__ batch, int* __restrict__ sg,
                            int* __restrict__ eg, int* __restrict__ rank, int n) {
    int i = blockIdx.x * blockDim.x + threadIdx.x;
    if (i < E) rank[i] = atomicAdd(&cnt[dst[i]], 1);
    if (i < n) {
        int b = batch[i];
        if (i == 0 || batch[i - 1] != b) sg[b] = i;
        if (i == n - 1 || batch[i + 1] != b) eg[b] = i + 1;
    }
}

// single-launch scan: block-local LDS scan + atomic ticket for block base.
// CSR segments need not be vertex-ordered -- any disjoint allocation works
// (fill computes slots from rank; agg reads [row_ptr, row_end)). Ticket =
// cnt[n] (zeroed by the cnt memset).
__global__ __launch_bounds__(256) void scan_one(const int* __restrict__ cnt,
        int* __restrict__ row_ptr, int* __restrict__ row_end,
        float* __restrict__ dis, int* __restrict__ ticket, int n) {
    __shared__ int s[256];
    __shared__ int base_sh;
    int t = threadIdx.x;
    int i = blockIdx.x * 256 + t;
    int c = (i < n) ? cnt[i] : 0;
    s[t] = c;
    __syncthreads();
    for (int off = 1; off < 256; off <<= 1) {
        int u = (t >= off) ? s[t - off] : 0;
        __syncthreads();
        s[t] += u;
        __syncthreads();
    }
    if (t == 255) base_sh = atomicAdd(ticket, s[255]);
    __syncthreads();
    if (i < n) {
        int ex = base_sh + s[t] - c;
        row_ptr[i] = ex;
        row_end[i] = ex + c;
        dis[i] = rsqrtf((float)c + 1.0f);   // +1 self-loop
    }
}

// merged fill + elementwise prep (one launch; both depend only on scan_one):
//   part 0: col_idx[row_ptr[d] + rank[e]] = src[e]       (E items, NO atomics)
//   part 1: xs[v][f] = fp8(8 * x[v][f] * dis[v])         (n*32 uint items)
//   part 2: WT1 bf16 [512][128]   <- q1_W1,q2_W1 (transposed)
//   part 3: WT2f fp8 [2][256][256] <- 8 * q{1,2}_W2 (transposed)
__global__ void fill_prep(const int* __restrict__ src, const int* __restrict__ dst,
                          const int* __restrict__ row_ptr, const int* __restrict__ rank,
                          int* __restrict__ col_idx, int E,
                          const float* __restrict__ x, const float* __restrict__ dis,
                          uchar* __restrict__ xs,
                          const float* __restrict__ W1a, const float* __restrict__ W1b,
                          const float* __restrict__ W2a, const float* __restrict__ W2b,
                          ushort* __restrict__ WT1, uchar* __restrict__ WT2f, int n) {
    int i = blockIdx.x * blockDim.x + threadIdx.x;
    if (i < E) {
        col_idx[row_ptr[dst[i]] + rank[i]] = src[i];
        return;
    }
    i -= E;
    const int nscale = n * (FEAT / 4);
    if (i < nscale) {
        int v = i >> 5;
        float dv = dis[v] * 8.f;
        float4 f = ((const float4*)x)[i];
        uint p = __builtin_amdgcn_cvt_pk_fp8_f32(f.x * dv, f.y * dv, 0, false);
        p = __builtin_amdgcn_cvt_pk_fp8_f32(f.z * dv, f.w * dv, p, true);
        ((uint*)xs)[i] = p;
        return;
    }
    i -= nscale;
    if (i < 2 * FEAT * HID) {
        int head = i >> 15;                  // /(128*256)
        int rem = i & 32767;
        int k = rem >> 8, nn = rem & 255;    // W1 [128][256]
        const float* W = head ? W1b : W1a;
        WT1[(size_t)(head * 256 + nn) * FEAT + k] = f2b(W[rem]);
    } else {
        int j = i - 2 * FEAT * HID;
        if (j >= 2 * HID * HID) return;
        int head = j >> 16;                  // /(256*256)
        int rem = j & 65535;
        int k = rem >> 8, nn = rem & 255;    // W2 [256][256]
        const float* W = head ? W2b : W2a;
        float v = W[rem] * 8.f;
        uint q = __builtin_amdgcn_cvt_pk_fp8_f32(v, v, 0, false);
        WT2f[(size_t)head * 65536 + nn * 256 + k] = (uchar)(q & 0xff);
    }
}

// ---------------------------------------------------------------------------
// agg128: z[v] = bf16((dis[v]/8) * (xs[v] + sum_{s in N(v)} xs[s]))  (fp8 in)
// simple unroll-8 (best measured; 4-edge restructure was neutral, reverted)
// ---------------------------------------------------------------------------

__global__ __launch_bounds__(256) void agg128(
        const uchar* __restrict__ xs, const float* __restrict__ dis,
        const int* __restrict__ row_ptr, const int* __restrict__ row_end,
        const int* __restrict__ col_idx,
        ushort* __restrict__ z, int n) {
    const int wave = threadIdx.x >> 6, lane = threadIdx.x & 63;
    const int v = blockIdx.x * 4 + wave;
    if (v >= n) return;
    const ushort* X = (const ushort*)xs;
    f32x2 p = upk_lo((uint)X[(size_t)v * 64 + lane]);
    float a0 = p[0], a1 = p[1];
    const int e0 = row_ptr[v], e1 = row_end[v];
    int e = e0;
    for (; e + 8 <= e1; e += 8) {
        uint m[8];
#pragma unroll
        for (int j = 0; j < 8; ++j) m[j] = X[(size_t)col_idx[e + j] * 64 + lane];
#pragma unroll
        for (int j = 0; j < 8; ++j) {
            f32x2 q = upk_lo(m[j]);
            a0 += q[0]; a1 += q[1];
        }
    }
    for (; e < e1; ++e) {
        f32x2 m = upk_lo((uint)X[(size_t)col_idx[e] * 64 + lane]);
        a0 += m[0]; a1 += m[1];
    }
    float sc = dis[v] * 0.125f;
    ((uint*)z)[(size_t)v * 64 + lane] = pack2(a0 * sc, a1 * sc);
}

// ---------------------------------------------------------------------------
// agg512: z2f[v][j] = fp8( (dis[v]/4) * (h1[v][j] + sum_{s} h1[s][j]) )
// simple unroll-8 (fabric-bound equilibrium). Launched as TWO half-range
// kernels (~30us each) so rocprof's top-5 can surface the other dispatches.
// ---------------------------------------------------------------------------

__global__ __launch_bounds__(256) void agg512(
        const uchar* __restrict__ h1, const float* __restrict__ dis,
        const int* __restrict__ row_ptr, const int* __restrict__ row_end,
        const int* __restrict__ col_idx,
        uchar* __restrict__ z2f, int v0, int nend) {
    const int wave = threadIdx.x >> 6, lane = threadIdx.x & 63;
    const int v = v0 + blockIdx.x * 4 + wave;
    if (v >= nend) return;
    const uint2* H = (const uint2*)h1;
    float acc[8];
    {
        uint2 g = H[(size_t)v * 64 + lane];
        f32x2 l0 = upk_lo(g.x), h0 = upk_hi(g.x);
        f32x2 l1 = upk_lo(g.y), h1v = upk_hi(g.y);
        acc[0] = l0[0]; acc[1] = l0[1]; acc[2] = h0[0]; acc[3] = h0[1];
        acc[4] = l1[0]; acc[5] = l1[1]; acc[6] = h1v[0]; acc[7] = h1v[1];
    }
    const int e0 = row_ptr[v], e1 = row_end[v];
    int e = e0;
    for (; e + 8 <= e1; e += 8) {
        uint2 m[8];
#pragma unroll
        for (int j = 0; j < 8; ++j) m[j] = H[(size_t)col_idx[e + j] * 64 + lane];
#pragma unroll
        for (int j = 0; j < 8; ++j) add8(acc, m[j]);
    }
    for (; e < e1; ++e) add8(acc, H[(size_t)col_idx[e] * 64 + lane]);
    float sc = dis[v] * 0.25f;
    uint lo = __builtin_amdgcn_cvt_pk_fp8_f32(acc[0] * sc, acc[1] * sc, 0, false);
    lo = __builtin_amdgcn_cvt_pk_fp8_f32(acc[2] * sc, acc[3] * sc, lo, true);
    uint hi = __builtin_amdgcn_cvt_pk_fp8_f32(acc[4] * sc, acc[5] * sc, 0, false);
    hi = __builtin_amdgcn_cvt_pk_fp8_f32(acc[6] * sc, acc[7] * sc, hi, true);
    uint2 o = {lo, hi};
    ((uint2*)z2f)[(size_t)v * 64 + lane] = o;
}

// ---------------------------------------------------------------------------
// GEMM1: h1[m][head*256+nl] = fp8( 16*dis[m]*relu(z[m].WT1[head*256+nl] + b1[nl]) )
// BM=128, 512 threads (4 row-waves x 2 col-waves; wave tile 32x128), K=128.
// B panel (64 KB bf16) staged in LDS; A read direct global->reg.
// MFMA operands SWAPPED (compute C^T) so each lane holds 4 consecutive n
// values -> fp8 output packed to dword stores (4x fewer, 4x better coalesce).
// ---------------------------------------------------------------------------

__global__ __launch_bounds__(512) void gemm1_mfma(
        const ushort* __restrict__ z,           // bf16 [M][128]
        const ushort* __restrict__ WT1,         // bf16 [512][128]
        const float* __restrict__ b1a, const float* __restrict__ b1b,
        const float* __restrict__ dis,
        uchar* __restrict__ out, int M) {       // h1 fp8 [M][512]
    constexpr int K = FEAT;                     // 128
    __shared__ char Bs[256 * 256];              // 64 KB bf16 B panel (swizzled)
    const int tid = threadIdx.x;
    const int bm = blockIdx.x * 128;
    const int head = blockIdx.y;
    const ushort* WT = WT1 + (size_t)head * 256 * K;
    const float* bias = head ? b1b : b1a;

    // stage B: 256 rows (n) x 16 segs of 16B, swizzled
    for (int idx = tid; idx < 256 * 16; idx += 512) {
        int nr = idx >> 4, seg = idx & 15;
        int4 val = *(const int4*)(WT + (size_t)nr * K + seg * 8);
        int byte = (nr * 256 + seg * 16) ^ ((nr & 7) << 4);
        *(int4*)(Bs + byte) = val;
    }
    __syncthreads();

    const int warp = tid >> 6, lane = tid & 63;
    const int wr = warp >> 1, wc = warp & 1;    // 4 row-waves x 2 col-waves
    const int kgrp = lane >> 4;
    const int r0 = wr * 32 + (lane & 15);       // + m*16 (block-local row, A side)
    const int c0 = wc * 128 + (lane & 15);      // + nf*16 (block-local col, B side)

    f32x4 acc[2][8] = {};
    const bf16x8 zv = {};
    for (int ks = 0; ks < 4; ++ks) {
        bf16x8 a[2], b[8];
#pragma unroll
        for (int m = 0; m < 2; ++m) {
            int grow = bm + r0 + m * 16;
            a[m] = (grow < M)
                 ? *(const bf16x8*)(z + (size_t)grow * K + ks * 32 + kgrp * 8)
                 : zv;
        }
#pragma unroll
        for (int nf = 0; nf < 8; ++nf) {
            int nr = c0 + nf * 16;
            int byte = (nr * 256 + ks * 64 + kgrp * 16) ^ ((nr & 7) << 4);
            b[nf] = *(const bf16x8*)(Bs + byte);
        }
        // swapped operands: D = C^T, so row-dim = n, col-dim = m
#pragma unroll
        for (int nf = 0; nf < 8; ++nf)
#pragma unroll
            for (int m = 0; m < 2; ++m)
                acc[m][nf] = __builtin_amdgcn_mfma_f32_16x16x32_bf16(b[nf], a[m], acc[m][nf], 0, 0, 0);
    }

    // epilogue: lane&15 -> m-row, (lane>>4)*4 + reg -> n  => pack 4 fp8 / dword
    const int ml = lane & 15;
    const int ngrp = (lane >> 4) * 4;
#pragma unroll
    for (int m = 0; m < 2; ++m) {
        int grow = bm + wr * 32 + m * 16 + ml;
        if (grow >= M) continue;
        float d = dis[grow] * 16.f;
#pragma unroll
        for (int nf = 0; nf < 8; ++nf) {
            int n0 = wc * 128 + nf * 16 + ngrp;
            float4 bv = *(const float4*)(bias + n0);
            f32x4 ac = acc[m][nf];
            float v0 = fmaxf(ac[0] + bv.x, 0.f) * d;
            float v1 = fmaxf(ac[1] + bv.y, 0.f) * d;
            float v2 = fmaxf(ac[2] + bv.z, 0.f) * d;
            float v3 = fmaxf(ac[3] + bv.w, 0.f) * d;
            uint q = __builtin_amdgcn_cvt_pk_fp8_f32(v0, v1, 0, false);
            q = __builtin_amdgcn_cvt_pk_fp8_f32(v2, v3, q, true);
            *(uint*)(out + (size_t)grow * 512 + head * 256 + n0) = q;
        }
    }
}

// ---------------------------------------------------------------------------
// GEMM2 (fp8 x fp8 MFMA) + fused mean-pool via shuffle reduction.
// BM=128, 512 threads (4 row-waves x 2 col-waves; wave tile 32x128), K=256.
// ---------------------------------------------------------------------------

__global__ __launch_bounds__(512) void gemm2_pool(
        const uchar* __restrict__ z2f,          // fp8 [M][512]
        const uchar* __restrict__ WT2f,         // fp8 [2][256][256]
        const float* __restrict__ b2a, const float* __restrict__ b2b,
        const int* __restrict__ batch,
        float* __restrict__ pooled, int M) {    // pooled [G][512]
    constexpr int K = HID;                      // 256
    __shared__ char Bs[256 * 256];              // 64 KB fp8 B panel (swizzled)
    __shared__ int rows_g[128];
    const int tid = threadIdx.x;
    const int bm = blockIdx.x * 128;
    const int head = blockIdx.y;
    const uchar* WT = WT2f + (size_t)head * 65536;
    const float* bias = head ? b2b : b2a;

    // stage B: 256 rows x 32 segs of 8B, swizzled at 8B granularity
    for (int idx = tid; idx < 256 * 32; idx += 512) {
        int nr = idx >> 5, seg = idx & 31;
        uint2 val = *(const uint2*)(WT + (size_t)nr * 256 + seg * 8);
        int byte = (nr * 256 + seg * 8) ^ ((nr & 7) << 3);
        *(uint2*)(Bs + byte) = val;
    }
    if (tid < 128) rows_g[tid] = batch[min(bm + tid, M - 1)];
    __syncthreads();

    const int warp = tid >> 6, lane = tid & 63;
    const int wr = warp >> 1, wc = warp & 1;    // 4 row-waves x 2 col-waves
    const int kgrp = lane >> 4;
    const int r0 = wr * 32 + (lane & 15);       // + m*16 (block-local row)
    const int c0 = wc * 128 + (lane & 15);      // + nf*16 (block-local col)
    const uchar* Abase = z2f + (size_t)head * 256;

    f32x4 acc[2][8] = {};
    for (int ks = 0; ks < 8; ++ks) {
        long a[2], b[8];
#pragma unroll
        for (int m = 0; m < 2; ++m) {
            int grow = bm + r0 + m * 16;
            a[m] = (grow < M)
                 ? *(const long*)(Abase + (size_t)grow * 512 + ks * 32 + kgrp * 8)
                 : 0L;
        }
#pragma unroll
        for (int nf = 0; nf < 8; ++nf) {
            int nr = c0 + nf * 16;
            int byte = (nr * 256 + ks * 32 + kgrp * 8) ^ ((nr & 7) << 3);
            b[nf] = *(const long*)(Bs + byte);
        }
#pragma unroll
        for (int nf = 0; nf < 8; ++nf)
#pragma unroll
            for (int m = 0; m < 2; ++m)
                acc[m][nf] = __builtin_amdgcn_mfma_f32_16x16x32_fp8_fp8(a[m], b[nf], acc[m][nf], 0, 0, 0);
    }

    // ---- fused pooling epilogue (wave's 32-row window spans <=2 graphs) ----
    const int rbw = wr * 32;
    const int g0 = rows_g[rbw];
    const int glast = rows_g[min(127, rbw + 31)];
    float s0[8] = {}, s1[8] = {};
#pragma unroll
    for (int m = 0; m < 2; ++m) {
#pragma unroll
        for (int r = 0; r < 4; ++r) {
            int lrow = rbw + m * 16 + (lane >> 4) * 4 + r;
            int grow = bm + lrow;
            if (grow < M) {
                bool in0 = (rows_g[lrow] == g0);
#pragma unroll
                for (int nf = 0; nf < 8; ++nf) {
                    float val = fmaxf(acc[m][nf][r] * 0.03125f + bias[c0 + nf * 16], 0.f);
                    if (in0) s0[nf] += val; else s1[nf] += val;
                }
            }
        }
    }
#pragma unroll
    for (int nf = 0; nf < 8; ++nf) {
        s0[nf] += __shfl_xor(s0[nf], 16, 64);
        s0[nf] += __shfl_xor(s0[nf], 32, 64);
        s1[nf] += __shfl_xor(s1[nf], 16, 64);
        s1[nf] += __shfl_xor(s1[nf], 32, 64);
    }
    if (kgrp == 0) {
#pragma unroll
        for (int nf = 0; nf < 8; ++nf) {
            int n = head * 256 + c0 + nf * 16;
            atomicAdd(&pooled[(size_t)g0 * 512 + n], s0[nf]);
            if (glast != g0) atomicAdd(&pooled[(size_t)glast * 512 + n], s1[nf]);
        }
    }
}

// final dot: 512 threads, head = t>>8, feature f = t&255
__global__ __launch_bounds__(512) void final_dot(
        const float* __restrict__ pooled, const int* __restrict__ sg,
        const int* __restrict__ eg, const float* __restrict__ action,
        const float* __restrict__ fcW1, const float* __restrict__ fcb1,
        const float* __restrict__ fcW2, const float* __restrict__ fcb2,
        float* __restrict__ out, int G) {
    int g = blockIdx.x, t = threadIdx.x;
    int head = t >> 8, f = t & 255;
    const float* fcW = head ? fcW2 : fcW1;
    float inv = 1.f / (float)(eg[g] - sg[g]);
    float p = pooled[g * 512 + t] * inv * fcW[f];
    if (f < ACTD) p += action[g * ACTD + f] * fcW[HID + f];
    for (int off = 32; off; off >>= 1) p += __shfl_down(p, off, 64);
    __shared__ float red[8];
    if ((t & 63) == 0) red[t >> 6] = p;
    __syncthreads();
    if (t == 0)   out[g]     = red[0] + red[1] + red[2] + red[3] + fcb1[0];
    if (t == 256) out[G + g] = red[4] + red[5] + red[6] + red[7] + fcb2[0];
}

// ---------------------------------------------------------------------------

extern "C" void kernel_launch(void* const* d_in, const int* in_sizes, int n_in,
                              void* d_out, int out_size, void* d_ws, size_t ws_size,
                              hipStream_t stream) {
    const float* x      = (const float*)d_in[0];
    const int*   ei     = (const int*)d_in[1];
    const int*   batch  = (const int*)d_in[2];
    const float* action = (const float*)d_in[3];
    const float* q1_W1  = (const float*)d_in[4];
    const float* q1_b1  = (const float*)d_in[5];
    const float* q1_W2  = (const float*)d_in[6];
    const float* q1_b2  = (const float*)d_in[7];
    const float* q1_fcW = (const float*)d_in[8];
    const float* q1_fcb = (const float*)d_in[9];
    const float* q2_W1  = (const float*)d_in[10];
    const float* q2_b1  = (const float*)d_in[11];
    const float* q2_W2  = (const float*)d_in[12];
    const float* q2_b2  = (const float*)d_in[13];
    const float* q2_fcW = (const float*)d_in[14];
    const float* q2_fcb = (const float*)d_in[15];

    const int N = in_sizes[2];
    const int E = in_sizes[1] / 2;
    const int G = in_sizes[3] / ACTD;
    const int* src = ei;
    const int* dst = ei + E;

    char* w = (char*)d_ws;
    size_t off = 0;
    auto take = [&](size_t bytes) -> void* {
        void* p = w + off;
        off = (off + bytes + 255) & ~(size_t)255;
        return p;
    };
    // cnt block: cnt[0..N-1], ticket=cnt[N]; pooled allocated immediately
    // after -> ONE memset zeroes both.
    int*    cnt      = (int*)take((size_t)(N + 1) * 4);
    float*  pooled   = (float*)take((size_t)G * 512 * 4);
    int*    row_ptr  = (int*)take((size_t)N * 4);
    int*    row_end  = (int*)take((size_t)N * 4);
    float*  dis      = (float*)take((size_t)N * 4);
    int*    rank     = (int*)take((size_t)E * 4);
    int*    col_idx  = (int*)take((size_t)E * 4);
    int*    sg       = (int*)take((size_t)G * 4);
    int*    eg       = (int*)take((size_t)G * 4);
    ushort* WT1      = (ushort*)take((size_t)512 * FEAT * 2);    // bf16 [512][128]
    uchar*  WT2f     = (uchar*)take((size_t)2 * HID * HID);      // fp8 [2][256][256]
    uchar*  xs       = (uchar*)take((size_t)N * FEAT);           // fp8
    ushort* z        = (ushort*)take((size_t)N * FEAT * 2);      // bf16
    uchar*  h1       = (uchar*)take((size_t)N * 512);            // fp8
    uchar*  z2f      = (uchar*)take((size_t)N * 512);            // fp8
    (void)ws_size;

    const int TB = 256;
    const int nb = (N + 255) / 256;
    size_t zlen = (size_t)((char*)pooled - (char*)cnt) + (size_t)G * 512 * 4;
    hipMemsetAsync(cnt, 0, zlen, stream);

    int hb_grid = (max(E, N) + TB - 1) / TB;
    hist_bounds<<<hb_grid, TB, 0, stream>>>(dst, cnt, E, batch, sg, eg, rank, N);
    scan_one<<<nb, TB, 0, stream>>>(cnt, row_ptr, row_end, dis, cnt + N, N);

    int fptotal = E + N * (FEAT / 4) + 2 * FEAT * HID + 2 * HID * HID;
    fill_prep<<<(fptotal + TB - 1) / TB, TB, 0, stream>>>(
        src, dst, row_ptr, rank, col_idx, E,
        x, dis, xs, q1_W1, q2_W1, q1_W2, q2_W2, WT1, WT2f, N);

    int agg_grid = (N + 3) / 4;
    int gx128 = (N + 127) / 128;

    agg128<<<agg_grid, TB, 0, stream>>>(xs, dis, row_ptr, row_end, col_idx, z, N);
    gemm1_mfma<<<dim3(gx128, 2), 512, 0, stream>>>(z, WT1, q1_b1, q2_b1, dis, h1, N);

    // agg512 split into two half-range launches (work-identical; gives the
    // rocprof top-5 table room to surface other dispatches)
    int half = ((N / 2) + 3) & ~3;
    agg512<<<(half + 3) / 4, TB, 0, stream>>>(h1, dis, row_ptr, row_end, col_idx,
                                              z2f, 0, half);
    agg512<<<(N - half + 3) / 4, TB, 0, stream>>>(h1, dis, row_ptr, row_end, col_idx,
                                                  z2f, half, N);

    gemm2_pool<<<dim3(gx128, 2), 512, 0, stream>>>(z2f, WT2f, q1_b2, q2_b2, batch,
                                                   pooled, N);
    final_dot<<<G, 512, 0, stream>>>(pooled, sg, eg, action,
                                     q1_fcW, q1_fcb, q2_fcW, q2_fcb,
                                     (float*)d_out, G);
}

// Round 9
// 234.143 us; speedup vs baseline: 1.1246x; 1.0031x over previous
//
#include <hip/hip_runtime.h>
#include <hip/hip_bf16.h>

#define FEAT 128
#define HID  256
#define ACTD 32

typedef __attribute__((ext_vector_type(8))) short bf16x8;
typedef __attribute__((ext_vector_type(4))) float f32x4;
typedef __attribute__((ext_vector_type(2))) float f32x2;

__device__ __forceinline__ ushort f2b(float f) {
    __hip_bfloat16 h = __float2bfloat16(f);
    return *(ushort*)&h;
}
__device__ __forceinline__ uint pack2(float lo, float hi) {
    return (uint)f2b(lo) | ((uint)f2b(hi) << 16);
}
// fp8 e4m3 helpers (hardware cvt; OCP on gfx950)
__device__ __forceinline__ f32x2 upk_lo(uint u) { return __builtin_amdgcn_cvt_pk_f32_fp8(u, false); }
__device__ __forceinline__ f32x2 upk_hi(uint u) { return __builtin_amdgcn_cvt_pk_f32_fp8(u, true); }

__device__ __forceinline__ void add8(float* acc, uint2 g) {
    f32x2 l0 = upk_lo(g.x), h0 = upk_hi(g.x);
    f32x2 l1 = upk_lo(g.y), h1 = upk_hi(g.y);
    acc[0] += l0[0]; acc[1] += l0[1]; acc[2] += h0[0]; acc[3] += h0[1];
    acc[4] += l1[0]; acc[5] += l1[1]; acc[6] += h1[0]; acc[7] += h1[1];
}

// ---------------------------------------------------------------------------
// workspace zeroing: hipMemsetAsync's fillBufferAligned helper measured
// 40+us (tiny fixed grid, 0.2 GB/s). This runs at memory speed.
// ---------------------------------------------------------------------------
__global__ void zero_ws(uint4* __restrict__ p, int n16) {
    int i = blockIdx.x * blockDim.x + threadIdx.x;
    if (i < n16) p[i] = uint4{0u, 0u, 0u, 0u};
}

// ---------------------------------------------------------------------------
// Graph preprocessing (separate launches: HW launch gaps are far cheaper than
// software grid barriers on MI355X -- R5 measured spin-barrier preproc at
// 360us from cross-XCD atomic line ping-pong)
// ---------------------------------------------------------------------------

// merged histogram + per-graph bounds. The atomic's return value IS the
// edge's rank within its destination row -> store it so the fill pass needs
// no atomics at all (R8 rank trick).
__global__ void hist_bounds(const int* __restrict__ dst, int* __restrict__ cnt, int E,
                            const int* __restrict__ batch, int* __restrict__ sg,
                            int* __restrict__ eg, int* __restrict__ rank, int n) {
    int i = blockIdx.x * blockDim.x + threadIdx.x;
    if (i < E) rank[i] = atomicAdd(&cnt[dst[i]], 1);
    if (i < n) {
        int b = batch[i];
        if (i == 0 || batch[i - 1] != b) sg[b] = i;
        if (i == n - 1 || batch[i + 1] != b) eg[b] = i + 1;
    }
}

// single-launch scan: block-local LDS scan + atomic ticket for block base.
// CSR segments need not be vertex-ordered -- any disjoint allocation works
// (fill computes slots from rank; agg reads [row_ptr, row_end)). Ticket =
// cnt[n] (zeroed by zero_ws).
__global__ __launch_bounds__(256) void scan_one(const int* __restrict__ cnt,
        int* __restrict__ row_ptr, int* __restrict__ row_end,
        float* __restrict__ dis, int* __restrict__ ticket, int n) {
    __shared__ int s[256];
    __shared__ int base_sh;
    int t = threadIdx.x;
    int i = blockIdx.x * 256 + t;
    int c = (i < n) ? cnt[i] : 0;
    s[t] = c;
    __syncthreads();
    for (int off = 1; off < 256; off <<= 1) {
        int u = (t >= off) ? s[t - off] : 0;
        __syncthreads();
        s[t] += u;
        __syncthreads();
    }
    if (t == 255) base_sh = atomicAdd(ticket, s[255]);
    __syncthreads();
    if (i < n) {
        int ex = base_sh + s[t] - c;
        row_ptr[i] = ex;
        row_end[i] = ex + c;
        dis[i] = rsqrtf((float)c + 1.0f);   // +1 self-loop
    }
}

// merged fill + elementwise prep (one launch; both depend only on scan_one):
//   part 0: col_idx[row_ptr[d] + rank[e]] = src[e]       (E items, NO atomics)
//   part 1: xs[v][f] = fp8(8 * x[v][f] * dis[v])         (n*32 uint items)
//   part 2: WT1 bf16 [512][128]   <- q1_W1,q2_W1 (transposed)
//   part 3: WT2f fp8 [2][256][256] <- 8 * q{1,2}_W2 (transposed)
__global__ void fill_prep(const int* __restrict__ src, const int* __restrict__ dst,
                          const int* __restrict__ row_ptr, const int* __restrict__ rank,
                          int* __restrict__ col_idx, int E,
                          const float* __restrict__ x, const float* __restrict__ dis,
                          uchar* __restrict__ xs,
                          const float* __restrict__ W1a, const float* __restrict__ W1b,
                          const float* __restrict__ W2a, const float* __restrict__ W2b,
                          ushort* __restrict__ WT1, uchar* __restrict__ WT2f, int n) {
    int i = blockIdx.x * blockDim.x + threadIdx.x;
    if (i < E) {
        col_idx[row_ptr[dst[i]] + rank[i]] = src[i];
        return;
    }
    i -= E;
    const int nscale = n * (FEAT / 4);
    if (i < nscale) {
        int v = i >> 5;
        float dv = dis[v] * 8.f;
        float4 f = ((const float4*)x)[i];
        uint p = __builtin_amdgcn_cvt_pk_fp8_f32(f.x * dv, f.y * dv, 0, false);
        p = __builtin_amdgcn_cvt_pk_fp8_f32(f.z * dv, f.w * dv, p, true);
        ((uint*)xs)[i] = p;
        return;
    }
    i -= nscale;
    if (i < 2 * FEAT * HID) {
        int head = i >> 15;                  // /(128*256)
        int rem = i & 32767;
        int k = rem >> 8, nn = rem & 255;    // W1 [128][256]
        const float* W = head ? W1b : W1a;
        WT1[(size_t)(head * 256 + nn) * FEAT + k] = f2b(W[rem]);
    } else {
        int j = i - 2 * FEAT * HID;
        if (j >= 2 * HID * HID) return;
        int head = j >> 16;                  // /(256*256)
        int rem = j & 65535;
        int k = rem >> 8, nn = rem & 255;    // W2 [256][256]
        const float* W = head ? W2b : W2a;
        float v = W[rem] * 8.f;
        uint q = __builtin_amdgcn_cvt_pk_fp8_f32(v, v, 0, false);
        WT2f[(size_t)head * 65536 + nn * 256 + k] = (uchar)(q & 0xff);
    }
}

// ---------------------------------------------------------------------------
// agg128: z[v] = bf16((dis[v]/8) * (xs[v] + sum_{s in N(v)} xs[s]))  (fp8 in)
// simple unroll-8 (best measured; 4-edge restructure was neutral, reverted)
// ---------------------------------------------------------------------------

__global__ __launch_bounds__(256) void agg128(
        const uchar* __restrict__ xs, const float* __restrict__ dis,
        const int* __restrict__ row_ptr, const int* __restrict__ row_end,
        const int* __restrict__ col_idx,
        ushort* __restrict__ z, int n) {
    const int wave = threadIdx.x >> 6, lane = threadIdx.x & 63;
    const int v = blockIdx.x * 4 + wave;
    if (v >= n) return;
    const ushort* X = (const ushort*)xs;
    f32x2 p = upk_lo((uint)X[(size_t)v * 64 + lane]);
    float a0 = p[0], a1 = p[1];
    const int e0 = row_ptr[v], e1 = row_end[v];
    int e = e0;
    for (; e + 8 <= e1; e += 8) {
        uint m[8];
#pragma unroll
        for (int j = 0; j < 8; ++j) m[j] = X[(size_t)col_idx[e + j] * 64 + lane];
#pragma unroll
        for (int j = 0; j < 8; ++j) {
            f32x2 q = upk_lo(m[j]);
            a0 += q[0]; a1 += q[1];
        }
    }
    for (; e < e1; ++e) {
        f32x2 m = upk_lo((uint)X[(size_t)col_idx[e] * 64 + lane]);
        a0 += m[0]; a1 += m[1];
    }
    float sc = dis[v] * 0.125f;
    ((uint*)z)[(size_t)v * 64 + lane] = pack2(a0 * sc, a1 * sc);
}

// ---------------------------------------------------------------------------
// agg512: z2f[v][j] = fp8( (dis[v]/4) * (h1[v][j] + sum_{s} h1[s][j]) )
// simple unroll-8 (fabric-bound equilibrium). Launched as TWO half-range
// kernels (~30us each) so rocprof's top-5 can surface the other dispatches.
// ---------------------------------------------------------------------------

__global__ __launch_bounds__(256) void agg512(
        const uchar* __restrict__ h1, const float* __restrict__ dis,
        const int* __restrict__ row_ptr, const int* __restrict__ row_end,
        const int* __restrict__ col_idx,
        uchar* __restrict__ z2f, int v0, int nend) {
    const int wave = threadIdx.x >> 6, lane = threadIdx.x & 63;
    const int v = v0 + blockIdx.x * 4 + wave;
    if (v >= nend) return;
    const uint2* H = (const uint2*)h1;
    float acc[8];
    {
        uint2 g = H[(size_t)v * 64 + lane];
        f32x2 l0 = upk_lo(g.x), h0 = upk_hi(g.x);
        f32x2 l1 = upk_lo(g.y), h1v = upk_hi(g.y);
        acc[0] = l0[0]; acc[1] = l0[1]; acc[2] = h0[0]; acc[3] = h0[1];
        acc[4] = l1[0]; acc[5] = l1[1]; acc[6] = h1v[0]; acc[7] = h1v[1];
    }
    const int e0 = row_ptr[v], e1 = row_end[v];
    int e = e0;
    for (; e + 8 <= e1; e += 8) {
        uint2 m[8];
#pragma unroll
        for (int j = 0; j < 8; ++j) m[j] = H[(size_t)col_idx[e + j] * 64 + lane];
#pragma unroll
        for (int j = 0; j < 8; ++j) add8(acc, m[j]);
    }
    for (; e < e1; ++e) add8(acc, H[(size_t)col_idx[e] * 64 + lane]);
    float sc = dis[v] * 0.25f;
    uint lo = __builtin_amdgcn_cvt_pk_fp8_f32(acc[0] * sc, acc[1] * sc, 0, false);
    lo = __builtin_amdgcn_cvt_pk_fp8_f32(acc[2] * sc, acc[3] * sc, lo, true);
    uint hi = __builtin_amdgcn_cvt_pk_fp8_f32(acc[4] * sc, acc[5] * sc, 0, false);
    hi = __builtin_amdgcn_cvt_pk_fp8_f32(acc[6] * sc, acc[7] * sc, hi, true);
    uint2 o = {lo, hi};
    ((uint2*)z2f)[(size_t)v * 64 + lane] = o;
}

// ---------------------------------------------------------------------------
// GEMM1: h1[m][head*256+nl] = fp8( 16*dis[m]*relu(z[m].WT1[head*256+nl] + b1[nl]) )
// BM=128, 512 threads (4 row-waves x 2 col-waves; wave tile 32x128), K=128.
// B panel (64 KB bf16) staged in LDS; A read direct global->reg.
// MFMA operands SWAPPED (compute C^T) so each lane holds 4 consecutive n
// values -> fp8 output packed to dword stores (4x fewer, 4x better coalesce).
// ---------------------------------------------------------------------------

__global__ __launch_bounds__(512) void gemm1_mfma(
        const ushort* __restrict__ z,           // bf16 [M][128]
        const ushort* __restrict__ WT1,         // bf16 [512][128]
        const float* __restrict__ b1a, const float* __restrict__ b1b,
        const float* __restrict__ dis,
        uchar* __restrict__ out, int M) {       // h1 fp8 [M][512]
    constexpr int K = FEAT;                     // 128
    __shared__ char Bs[256 * 256];              // 64 KB bf16 B panel (swizzled)
    const int tid = threadIdx.x;
    const int bm = blockIdx.x * 128;
    const int head = blockIdx.y;
    const ushort* WT = WT1 + (size_t)head * 256 * K;
    const float* bias = head ? b1b : b1a;

    // stage B: 256 rows (n) x 16 segs of 16B, swizzled
    for (int idx = tid; idx < 256 * 16; idx += 512) {
        int nr = idx >> 4, seg = idx & 15;
        int4 val = *(const int4*)(WT + (size_t)nr * K + seg * 8);
        int byte = (nr * 256 + seg * 16) ^ ((nr & 7) << 4);
        *(int4*)(Bs + byte) = val;
    }
    __syncthreads();

    const int warp = tid >> 6, lane = tid & 63;
    const int wr = warp >> 1, wc = warp & 1;    // 4 row-waves x 2 col-waves
    const int kgrp = lane >> 4;
    const int r0 = wr * 32 + (lane & 15);       // + m*16 (block-local row, A side)
    const int c0 = wc * 128 + (lane & 15);      // + nf*16 (block-local col, B side)

    f32x4 acc[2][8] = {};
    const bf16x8 zv = {};
    for (int ks = 0; ks < 4; ++ks) {
        bf16x8 a[2], b[8];
#pragma unroll
        for (int m = 0; m < 2; ++m) {
            int grow = bm + r0 + m * 16;
            a[m] = (grow < M)
                 ? *(const bf16x8*)(z + (size_t)grow * K + ks * 32 + kgrp * 8)
                 : zv;
        }
#pragma unroll
        for (int nf = 0; nf < 8; ++nf) {
            int nr = c0 + nf * 16;
            int byte = (nr * 256 + ks * 64 + kgrp * 16) ^ ((nr & 7) << 4);
            b[nf] = *(const bf16x8*)(Bs + byte);
        }
        // swapped operands: D = C^T, so row-dim = n, col-dim = m
#pragma unroll
        for (int nf = 0; nf < 8; ++nf)
#pragma unroll
            for (int m = 0; m < 2; ++m)
                acc[m][nf] = __builtin_amdgcn_mfma_f32_16x16x32_bf16(b[nf], a[m], acc[m][nf], 0, 0, 0);
    }

    // epilogue: lane&15 -> m-row, (lane>>4)*4 + reg -> n  => pack 4 fp8 / dword
    const int ml = lane & 15;
    const int ngrp = (lane >> 4) * 4;
#pragma unroll
    for (int m = 0; m < 2; ++m) {
        int grow = bm + wr * 32 + m * 16 + ml;
        if (grow >= M) continue;
        float d = dis[grow] * 16.f;
#pragma unroll
        for (int nf = 0; nf < 8; ++nf) {
            int n0 = wc * 128 + nf * 16 + ngrp;
            float4 bv = *(const float4*)(bias + n0);
            f32x4 ac = acc[m][nf];
            float v0 = fmaxf(ac[0] + bv.x, 0.f) * d;
            float v1 = fmaxf(ac[1] + bv.y, 0.f) * d;
            float v2 = fmaxf(ac[2] + bv.z, 0.f) * d;
            float v3 = fmaxf(ac[3] + bv.w, 0.f) * d;
            uint q = __builtin_amdgcn_cvt_pk_fp8_f32(v0, v1, 0, false);
            q = __builtin_amdgcn_cvt_pk_fp8_f32(v2, v3, q, true);
            *(uint*)(out + (size_t)grow * 512 + head * 256 + n0) = q;
        }
    }
}

// ---------------------------------------------------------------------------
// GEMM2 (fp8 x fp8 MFMA) + fused mean-pool via shuffle reduction.
// BM=128, 512 threads (4 row-waves x 2 col-waves; wave tile 32x128), K=256.
// B panel LDS layout: per-row ROTATION swizzle -- chunk c of row nr stored at
// slot (c + 2*nr)&31 (8B granularity). Old XOR swizzle collapsed reads onto
// 8 slots (8-way conflict, 2.4M SQ_LDS_BANK_CONFLICT); rotation gives 32
// distinct slots / 2 lanes each = free (R9).
// ---------------------------------------------------------------------------

__global__ __launch_bounds__(512) void gemm2_pool(
        const uchar* __restrict__ z2f,          // fp8 [M][512]
        const uchar* __restrict__ WT2f,         // fp8 [2][256][256]
        const float* __restrict__ b2a, const float* __restrict__ b2b,
        const int* __restrict__ batch,
        float* __restrict__ pooled, int M) {    // pooled [G][512]
    __shared__ char Bs[256 * 256];              // 64 KB fp8 B panel (rotated)
    __shared__ int rows_g[128];
    const int tid = threadIdx.x;
    const int bm = blockIdx.x * 128;
    const int head = blockIdx.y;
    const uchar* WT = WT2f + (size_t)head * 65536;
    const float* bias = head ? b2b : b2a;

    // stage B: 256 rows x 32 chunks of 8B, rotated
    for (int idx = tid; idx < 256 * 32; idx += 512) {
        int nr = idx >> 5, seg = idx & 31;
        uint2 val = *(const uint2*)(WT + (size_t)nr * 256 + seg * 8);
        int slot = (seg + 2 * nr) & 31;
        *(uint2*)(Bs + nr * 256 + slot * 8) = val;
    }
    if (tid < 128) rows_g[tid] = batch[min(bm + tid, M - 1)];
    __syncthreads();

    const int warp = tid >> 6, lane = tid & 63;
    const int wr = warp >> 1, wc = warp & 1;    // 4 row-waves x 2 col-waves
    const int kgrp = lane >> 4;
    const int r0 = wr * 32 + (lane & 15);       // + m*16 (block-local row)
    const int c0 = wc * 128 + (lane & 15);      // + nf*16 (block-local col)
    const uchar* Abase = z2f + (size_t)head * 256;

    f32x4 acc[2][8] = {};
    for (int ks = 0; ks < 8; ++ks) {
        long a[2], b[8];
#pragma unroll
        for (int m = 0; m < 2; ++m) {
            int grow = bm + r0 + m * 16;
            a[m] = (grow < M)
                 ? *(const long*)(Abase + (size_t)grow * 512 + ks * 32 + kgrp * 8)
                 : 0L;
        }
#pragma unroll
        for (int nf = 0; nf < 8; ++nf) {
            int nr = c0 + nf * 16;
            int slot = (ks * 4 + kgrp + 2 * nr) & 31;
            b[nf] = *(const long*)(Bs + nr * 256 + slot * 8);
        }
#pragma unroll
        for (int nf = 0; nf < 8; ++nf)
#pragma unroll
            for (int m = 0; m < 2; ++m)
                acc[m][nf] = __builtin_amdgcn_mfma_f32_16x16x32_fp8_fp8(a[m], b[nf], acc[m][nf], 0, 0, 0);
    }

    // ---- fused pooling epilogue (wave's 32-row window spans <=2 graphs) ----
    const int rbw = wr * 32;
    const int g0 = rows_g[rbw];
    const int glast = rows_g[min(127, rbw + 31)];
    float s0[8] = {}, s1[8] = {};
#pragma unroll
    for (int m = 0; m < 2; ++m) {
#pragma unroll
        for (int r = 0; r < 4; ++r) {
            int lrow = rbw + m * 16 + (lane >> 4) * 4 + r;
            int grow = bm + lrow;
            if (grow < M) {
                bool in0 = (rows_g[lrow] == g0);
#pragma unroll
                for (int nf = 0; nf < 8; ++nf) {
                    float val = fmaxf(acc[m][nf][r] * 0.03125f + bias[c0 + nf * 16], 0.f);
                    if (in0) s0[nf] += val; else s1[nf] += val;
                }
            }
        }
    }
#pragma unroll
    for (int nf = 0; nf < 8; ++nf) {
        s0[nf] += __shfl_xor(s0[nf], 16, 64);
        s0[nf] += __shfl_xor(s0[nf], 32, 64);
        s1[nf] += __shfl_xor(s1[nf], 16, 64);
        s1[nf] += __shfl_xor(s1[nf], 32, 64);
    }
    if (kgrp == 0) {
#pragma unroll
        for (int nf = 0; nf < 8; ++nf) {
            int n = head * 256 + c0 + nf * 16;
            atomicAdd(&pooled[(size_t)g0 * 512 + n], s0[nf]);
            if (glast != g0) atomicAdd(&pooled[(size_t)glast * 512 + n], s1[nf]);
        }
    }
}

// final dot: 512 threads, head = t>>8, feature f = t&255
__global__ __launch_bounds__(512) void final_dot(
        const float* __restrict__ pooled, const int* __restrict__ sg,
        const int* __restrict__ eg, const float* __restrict__ action,
        const float* __restrict__ fcW1, const float* __restrict__ fcb1,
        const float* __restrict__ fcW2, const float* __restrict__ fcb2,
        float* __restrict__ out, int G) {
    int g = blockIdx.x, t = threadIdx.x;
    int head = t >> 8, f = t & 255;
    const float* fcW = head ? fcW2 : fcW1;
    float inv = 1.f / (float)(eg[g] - sg[g]);
    float p = pooled[g * 512 + t] * inv * fcW[f];
    if (f < ACTD) p += action[g * ACTD + f] * fcW[HID + f];
    for (int off = 32; off; off >>= 1) p += __shfl_down(p, off, 64);
    __shared__ float red[8];
    if ((t & 63) == 0) red[t >> 6] = p;
    __syncthreads();
    if (t == 0)   out[g]     = red[0] + red[1] + red[2] + red[3] + fcb1[0];
    if (t == 256) out[G + g] = red[4] + red[5] + red[6] + red[7] + fcb2[0];
}

// ---------------------------------------------------------------------------

extern "C" void kernel_launch(void* const* d_in, const int* in_sizes, int n_in,
                              void* d_out, int out_size, void* d_ws, size_t ws_size,
                              hipStream_t stream) {
    const float* x      = (const float*)d_in[0];
    const int*   ei     = (const int*)d_in[1];
    const int*   batch  = (const int*)d_in[2];
    const float* action = (const float*)d_in[3];
    const float* q1_W1  = (const float*)d_in[4];
    const float* q1_b1  = (const float*)d_in[5];
    const float* q1_W2  = (const float*)d_in[6];
    const float* q1_b2  = (const float*)d_in[7];
    const float* q1_fcW = (const float*)d_in[8];
    const float* q1_fcb = (const float*)d_in[9];
    const float* q2_W1  = (const float*)d_in[10];
    const float* q2_b1  = (const float*)d_in[11];
    const float* q2_W2  = (const float*)d_in[12];
    const float* q2_b2  = (const float*)d_in[13];
    const float* q2_fcW = (const float*)d_in[14];
    const float* q2_fcb = (const float*)d_in[15];

    const int N = in_sizes[2];
    const int E = in_sizes[1] / 2;
    const int G = in_sizes[3] / ACTD;
    const int* src = ei;
    const int* dst = ei + E;

    char* w = (char*)d_ws;
    size_t off = 0;
    auto take = [&](size_t bytes) -> void* {
        void* p = w + off;
        off = (off + bytes + 255) & ~(size_t)255;
        return p;
    };
    // cnt block: cnt[0..N-1], ticket=cnt[N]; pooled allocated immediately
    // after -> ONE zero_ws pass clears both.
    int*    cnt      = (int*)take((size_t)(N + 1) * 4);
    float*  pooled   = (float*)take((size_t)G * 512 * 4);
    int*    row_ptr  = (int*)take((size_t)N * 4);
    int*    row_end  = (int*)take((size_t)N * 4);
    float*  dis      = (float*)take((size_t)N * 4);
    int*    rank     = (int*)take((size_t)E * 4);
    int*    col_idx  = (int*)take((size_t)E * 4);
    int*    sg       = (int*)take((size_t)G * 4);
    int*    eg       = (int*)take((size_t)G * 4);
    ushort* WT1      = (ushort*)take((size_t)512 * FEAT * 2);    // bf16 [512][128]
    uchar*  WT2f     = (uchar*)take((size_t)2 * HID * HID);      // fp8 [2][256][256]
    uchar*  xs       = (uchar*)take((size_t)N * FEAT);           // fp8
    ushort* z        = (ushort*)take((size_t)N * FEAT * 2);      // bf16
    uchar*  h1       = (uchar*)take((size_t)N * 512);            // fp8
    uchar*  z2f      = (uchar*)take((size_t)N * 512);            // fp8
    (void)ws_size;

    const int TB = 256;
    const int nb = (N + 255) / 256;
    size_t zlen = (size_t)((char*)pooled - (char*)cnt) + (size_t)G * 512 * 4;
    int n16 = (int)((zlen + 15) / 16);
    zero_ws<<<(n16 + TB - 1) / TB, TB, 0, stream>>>((uint4*)cnt, n16);

    int hb_grid = (max(E, N) + TB - 1) / TB;
    hist_bounds<<<hb_grid, TB, 0, stream>>>(dst, cnt, E, batch, sg, eg, rank, N);
    scan_one<<<nb, TB, 0, stream>>>(cnt, row_ptr, row_end, dis, cnt + N, N);

    int fptotal = E + N * (FEAT / 4) + 2 * FEAT * HID + 2 * HID * HID;
    fill_prep<<<(fptotal + TB - 1) / TB, TB, 0, stream>>>(
        src, dst, row_ptr, rank, col_idx, E,
        x, dis, xs, q1_W1, q2_W1, q1_W2, q2_W2, WT1, WT2f, N);

    int agg_grid = (N + 3) / 4;
    int gx128 = (N + 127) / 128;

    agg128<<<agg_grid, TB, 0, stream>>>(xs, dis, row_ptr, row_end, col_idx, z, N);
    gemm1_mfma<<<dim3(gx128, 2), 512, 0, stream>>>(z, WT1, q1_b1, q2_b1, dis, h1, N);

    // agg512 split into two half-range launches (work-identical; gives the
    // rocprof top-5 table room to surface other dispatches)
    int half = ((N / 2) + 3) & ~3;
    agg512<<<(half + 3) / 4, TB, 0, stream>>>(h1, dis, row_ptr, row_end, col_idx,
                                              z2f, 0, half);
    agg512<<<(N - half + 3) / 4, TB, 0, stream>>>(h1, dis, row_ptr, row_end, col_idx,
                                                  z2f, half, N);

    gemm2_pool<<<dim3(gx128, 2), 512, 0, stream>>>(z2f, WT2f, q1_b2, q2_b2, batch,
                                                   pooled, N);
    final_dot<<<G, 512, 0, stream>>>(pooled, sg, eg, action,
                                     q1_fcW, q1_fcb, q2_fcW, q2_fcb,
                                     (float*)d_out, G);
}

// Round 10
// 224.312 us; speedup vs baseline: 1.1739x; 1.0438x over previous
//
#include <hip/hip_runtime.h>
#include <hip/hip_bf16.h>

#define FEAT 128
#define HID  256
#define ACTD 32

typedef __attribute__((ext_vector_type(8))) short bf16x8;
typedef __attribute__((ext_vector_type(4))) float f32x4;
typedef __attribute__((ext_vector_type(2))) float f32x2;

__device__ __forceinline__ ushort f2b(float f) {
    __hip_bfloat16 h = __float2bfloat16(f);
    return *(ushort*)&h;
}
__device__ __forceinline__ uint pack2(float lo, float hi) {
    return (uint)f2b(lo) | ((uint)f2b(hi) << 16);
}
// fp8 e4m3 helpers (hardware cvt; OCP on gfx950)
__device__ __forceinline__ f32x2 upk_lo(uint u) { return __builtin_amdgcn_cvt_pk_f32_fp8(u, false); }
__device__ __forceinline__ f32x2 upk_hi(uint u) { return __builtin_amdgcn_cvt_pk_f32_fp8(u, true); }

__device__ __forceinline__ void add8(float* acc, uint2 g) {
    f32x2 l0 = upk_lo(g.x), h0 = upk_hi(g.x);
    f32x2 l1 = upk_lo(g.y), h1 = upk_hi(g.y);
    acc[0] += l0[0]; acc[1] += l0[1]; acc[2] += h0[0]; acc[3] += h0[1];
    acc[4] += l1[0]; acc[5] += l1[1]; acc[6] += h1[0]; acc[7] += h1[1];
}

// ---------------------------------------------------------------------------
// workspace zeroing (only the ~331KB cnt+pooled block; runs at memory speed)
// ---------------------------------------------------------------------------
__global__ void zero_ws(uint4* __restrict__ p, int n16) {
    int i = blockIdx.x * blockDim.x + threadIdx.x;
    if (i < n16) p[i] = uint4{0u, 0u, 0u, 0u};
}

// ---------------------------------------------------------------------------
// Graph preprocessing (separate launches: HW launch gaps are far cheaper than
// software grid barriers on MI355X -- R5 measured spin-barrier preproc at
// 360us from cross-XCD atomic line ping-pong)
// ---------------------------------------------------------------------------

// merged histogram + per-graph bounds. The atomic's return value IS the
// edge's rank within its destination row -> fill pass needs no atomics.
__global__ void hist_bounds(const int* __restrict__ dst, int* __restrict__ cnt, int E,
                            const int* __restrict__ batch, int* __restrict__ sg,
                            int* __restrict__ eg, int* __restrict__ rank, int n) {
    int i = blockIdx.x * blockDim.x + threadIdx.x;
    if (i < E) rank[i] = atomicAdd(&cnt[dst[i]], 1);
    if (i < n) {
        int b = batch[i];
        if (i == 0 || batch[i - 1] != b) sg[b] = i;
        if (i == n - 1 || batch[i + 1] != b) eg[b] = i + 1;
    }
}

// single-launch scan: block-local LDS scan + atomic ticket for block base.
// CSR segments need not be vertex-ordered -- any disjoint allocation works.
__global__ __launch_bounds__(256) void scan_one(const int* __restrict__ cnt,
        int* __restrict__ row_ptr, int* __restrict__ row_end,
        float* __restrict__ dis, int* __restrict__ ticket, int n) {
    __shared__ int s[256];
    __shared__ int base_sh;
    int t = threadIdx.x;
    int i = blockIdx.x * 256 + t;
    int c = (i < n) ? cnt[i] : 0;
    s[t] = c;
    __syncthreads();
    for (int off = 1; off < 256; off <<= 1) {
        int u = (t >= off) ? s[t - off] : 0;
        __syncthreads();
        s[t] += u;
        __syncthreads();
    }
    if (t == 255) base_sh = atomicAdd(ticket, s[255]);
    __syncthreads();
    if (i < n) {
        int ex = base_sh + s[t] - c;
        row_ptr[i] = ex;
        row_end[i] = ex + c;
        dis[i] = rsqrtf((float)c + 1.0f);   // +1 self-loop
    }
}

// merged fill + elementwise prep (one launch; both depend only on scan_one)
__global__ void fill_prep(const int* __restrict__ src, const int* __restrict__ dst,
                          const int* __restrict__ row_ptr, const int* __restrict__ rank,
                          int* __restrict__ col_idx, int E,
                          const float* __restrict__ x, const float* __restrict__ dis,
                          uchar* __restrict__ xs,
                          const float* __restrict__ W1a, const float* __restrict__ W1b,
                          const float* __restrict__ W2a, const float* __restrict__ W2b,
                          ushort* __restrict__ WT1, uchar* __restrict__ WT2f, int n) {
    int i = blockIdx.x * blockDim.x + threadIdx.x;
    if (i < E) {
        col_idx[row_ptr[dst[i]] + rank[i]] = src[i];
        return;
    }
    i -= E;
    const int nscale = n * (FEAT / 4);
    if (i < nscale) {
        int v = i >> 5;
        float dv = dis[v] * 8.f;
        float4 f = ((const float4*)x)[i];
        uint p = __builtin_amdgcn_cvt_pk_fp8_f32(f.x * dv, f.y * dv, 0, false);
        p = __builtin_amdgcn_cvt_pk_fp8_f32(f.z * dv, f.w * dv, p, true);
        ((uint*)xs)[i] = p;
        return;
    }
    i -= nscale;
    if (i < 2 * FEAT * HID) {
        int head = i >> 15;                  // /(128*256)
        int rem = i & 32767;
        int k = rem >> 8, nn = rem & 255;    // W1 [128][256]
        const float* W = head ? W1b : W1a;
        WT1[(size_t)(head * 256 + nn) * FEAT + k] = f2b(W[rem]);
    } else {
        int j = i - 2 * FEAT * HID;
        if (j >= 2 * HID * HID) return;
        int head = j >> 16;                  // /(256*256)
        int rem = j & 65535;
        int k = rem >> 8, nn = rem & 255;    // W2 [256][256]
        const float* W = head ? W2b : W2a;
        float v = W[rem] * 8.f;
        uint q = __builtin_amdgcn_cvt_pk_fp8_f32(v, v, 0, false);
        WT2f[(size_t)head * 65536 + nn * 256 + k] = (uchar)(q & 0xff);
    }
}

// ---------------------------------------------------------------------------
// agg128: z[v] = bf16((dis[v]/8) * (xs[v] + sum_{s in N(v)} xs[s]))  (fp8 in)
// simple unroll-8 (best measured; 4-edge restructure was neutral, reverted)
// ---------------------------------------------------------------------------

__global__ __launch_bounds__(256) void agg128(
        const uchar* __restrict__ xs, const float* __restrict__ dis,
        const int* __restrict__ row_ptr, const int* __restrict__ row_end,
        const int* __restrict__ col_idx,
        ushort* __restrict__ z, int n) {
    const int wave = threadIdx.x >> 6, lane = threadIdx.x & 63;
    const int v = blockIdx.x * 4 + wave;
    if (v >= n) return;
    const ushort* X = (const ushort*)xs;
    f32x2 p = upk_lo((uint)X[(size_t)v * 64 + lane]);
    float a0 = p[0], a1 = p[1];
    const int e0 = row_ptr[v], e1 = row_end[v];
    int e = e0;
    for (; e + 8 <= e1; e += 8) {
        uint m[8];
#pragma unroll
        for (int j = 0; j < 8; ++j) m[j] = X[(size_t)col_idx[e + j] * 64 + lane];
#pragma unroll
        for (int j = 0; j < 8; ++j) {
            f32x2 q = upk_lo(m[j]);
            a0 += q[0]; a1 += q[1];
        }
    }
    for (; e < e1; ++e) {
        f32x2 m = upk_lo((uint)X[(size_t)col_idx[e] * 64 + lane]);
        a0 += m[0]; a1 += m[1];
    }
    float sc = dis[v] * 0.125f;
    ((uint*)z)[(size_t)v * 64 + lane] = pack2(a0 * sc, a1 * sc);
}

// ---------------------------------------------------------------------------
// agg512: z2f[slab][v][32B] = fp8( (dis[v]/4) * (h1[v] + sum_s h1[s]) )
// Output in K-SLAB-MAJOR layout (slab = k/32, 16 slabs of 32B): gemm2's A
// loads then read 16 rows x 32B CONTIGUOUS = one coalesced 512B wave txn
// (R10; was 16 scattered 32B segments per load instr). agg512's store
// becomes 16x32B scatter -- stores are fire-and-forget, negligible.
// ---------------------------------------------------------------------------

__global__ __launch_bounds__(256) void agg512(
        const uchar* __restrict__ h1, const float* __restrict__ dis,
        const int* __restrict__ row_ptr, const int* __restrict__ row_end,
        const int* __restrict__ col_idx,
        uchar* __restrict__ z2f, int n) {
    const int wave = threadIdx.x >> 6, lane = threadIdx.x & 63;
    const int v = blockIdx.x * 4 + wave;
    if (v >= n) return;
    const uint2* H = (const uint2*)h1;
    float acc[8];
    {
        uint2 g = H[(size_t)v * 64 + lane];
        f32x2 l0 = upk_lo(g.x), h0 = upk_hi(g.x);
        f32x2 l1 = upk_lo(g.y), h1v = upk_hi(g.y);
        acc[0] = l0[0]; acc[1] = l0[1]; acc[2] = h0[0]; acc[3] = h0[1];
        acc[4] = l1[0]; acc[5] = l1[1]; acc[6] = h1v[0]; acc[7] = h1v[1];
    }
    const int e0 = row_ptr[v], e1 = row_end[v];
    int e = e0;
    for (; e + 8 <= e1; e += 8) {
        uint2 m[8];
#pragma unroll
        for (int j = 0; j < 8; ++j) m[j] = H[(size_t)col_idx[e + j] * 64 + lane];
#pragma unroll
        for (int j = 0; j < 8; ++j) add8(acc, m[j]);
    }
    for (; e < e1; ++e) add8(acc, H[(size_t)col_idx[e] * 64 + lane]);
    float sc = dis[v] * 0.25f;
    uint lo = __builtin_amdgcn_cvt_pk_fp8_f32(acc[0] * sc, acc[1] * sc, 0, false);
    lo = __builtin_amdgcn_cvt_pk_fp8_f32(acc[2] * sc, acc[3] * sc, lo, true);
    uint hi = __builtin_amdgcn_cvt_pk_fp8_f32(acc[4] * sc, acc[5] * sc, 0, false);
    hi = __builtin_amdgcn_cvt_pk_fp8_f32(acc[6] * sc, acc[7] * sc, hi, true);
    uint2 o = {lo, hi};
    // K-slab-major store: lane covers global k in [lane*8, lane*8+8)
    // slab = lane>>2 (32B slabs), offset within slab = (lane&3)*8
    ((uint2*)z2f)[((size_t)(lane >> 2) * n + v) * 4 + (lane & 3)] = o;
}

// ---------------------------------------------------------------------------
// GEMM1: h1[m][head*256+nl] = fp8( 16*dis[m]*relu(z[m].WT1[head*256+nl] + b1[nl]) )
// BM=128, 512 threads (4 row-waves x 2 col-waves; wave tile 32x128), K=128.
// B panel (64 KB bf16) staged in LDS; A read direct global->reg.
// MFMA operands SWAPPED (compute C^T) so each lane holds 4 consecutive n
// values -> fp8 output packed to dword stores.
// ---------------------------------------------------------------------------

__global__ __launch_bounds__(512) void gemm1_mfma(
        const ushort* __restrict__ z,           // bf16 [M][128]
        const ushort* __restrict__ WT1,         // bf16 [512][128]
        const float* __restrict__ b1a, const float* __restrict__ b1b,
        const float* __restrict__ dis,
        uchar* __restrict__ out, int M) {       // h1 fp8 [M][512]
    constexpr int K = FEAT;                     // 128
    __shared__ char Bs[256 * 256];              // 64 KB bf16 B panel (swizzled)
    const int tid = threadIdx.x;
    const int bm = blockIdx.x * 128;
    const int head = blockIdx.y;
    const ushort* WT = WT1 + (size_t)head * 256 * K;
    const float* bias = head ? b1b : b1a;

    // stage B: 256 rows (n) x 16 segs of 16B, swizzled
    for (int idx = tid; idx < 256 * 16; idx += 512) {
        int nr = idx >> 4, seg = idx & 15;
        int4 val = *(const int4*)(WT + (size_t)nr * K + seg * 8);
        int byte = (nr * 256 + seg * 16) ^ ((nr & 7) << 4);
        *(int4*)(Bs + byte) = val;
    }
    __syncthreads();

    const int warp = tid >> 6, lane = tid & 63;
    const int wr = warp >> 1, wc = warp & 1;    // 4 row-waves x 2 col-waves
    const int kgrp = lane >> 4;
    const int r0 = wr * 32 + (lane & 15);       // + m*16 (block-local row, A side)
    const int c0 = wc * 128 + (lane & 15);      // + nf*16 (block-local col, B side)

    f32x4 acc[2][8] = {};
    const bf16x8 zv = {};
    for (int ks = 0; ks < 4; ++ks) {
        bf16x8 a[2], b[8];
#pragma unroll
        for (int m = 0; m < 2; ++m) {
            int grow = bm + r0 + m * 16;
            a[m] = (grow < M)
                 ? *(const bf16x8*)(z + (size_t)grow * K + ks * 32 + kgrp * 8)
                 : zv;
        }
#pragma unroll
        for (int nf = 0; nf < 8; ++nf) {
            int nr = c0 + nf * 16;
            int byte = (nr * 256 + ks * 64 + kgrp * 16) ^ ((nr & 7) << 4);
            b[nf] = *(const bf16x8*)(Bs + byte);
        }
        // swapped operands: D = C^T, so row-dim = n, col-dim = m
#pragma unroll
        for (int nf = 0; nf < 8; ++nf)
#pragma unroll
            for (int m = 0; m < 2; ++m)
                acc[m][nf] = __builtin_amdgcn_mfma_f32_16x16x32_bf16(b[nf], a[m], acc[m][nf], 0, 0, 0);
    }

    // epilogue: lane&15 -> m-row, (lane>>4)*4 + reg -> n  => pack 4 fp8 / dword
    const int ml = lane & 15;
    const int ngrp = (lane >> 4) * 4;
#pragma unroll
    for (int m = 0; m < 2; ++m) {
        int grow = bm + wr * 32 + m * 16 + ml;
        if (grow >= M) continue;
        float d = dis[grow] * 16.f;
#pragma unroll
        for (int nf = 0; nf < 8; ++nf) {
            int n0 = wc * 128 + nf * 16 + ngrp;
            float4 bv = *(const float4*)(bias + n0);
            f32x4 ac = acc[m][nf];
            float v0 = fmaxf(ac[0] + bv.x, 0.f) * d;
            float v1 = fmaxf(ac[1] + bv.y, 0.f) * d;
            float v2 = fmaxf(ac[2] + bv.z, 0.f) * d;
            float v3 = fmaxf(ac[3] + bv.w, 0.f) * d;
            uint q = __builtin_amdgcn_cvt_pk_fp8_f32(v0, v1, 0, false);
            q = __builtin_amdgcn_cvt_pk_fp8_f32(v2, v3, q, true);
            *(uint*)(out + (size_t)grow * 512 + head * 256 + n0) = q;
        }
    }
}

// ---------------------------------------------------------------------------
// GEMM2 (fp8 x fp8 MFMA) + fused mean-pool via shuffle reduction.
// BM=128, 512 threads (4 row-waves x 2 col-waves; wave tile 32x128), K=256.
// A (z2f) is K-slab-major -> fully coalesced 512B A loads (R10).
// B panel: per-row rotation swizzle (conflict-free, R9).
// ---------------------------------------------------------------------------

__global__ __launch_bounds__(512) void gemm2_pool(
        const uchar* __restrict__ z2f,          // fp8 [16 slabs][M][32]
        const uchar* __restrict__ WT2f,         // fp8 [2][256][256]
        const float* __restrict__ b2a, const float* __restrict__ b2b,
        const int* __restrict__ batch,
        float* __restrict__ pooled, int M) {    // pooled [G][512]
    __shared__ char Bs[256 * 256];              // 64 KB fp8 B panel (rotated)
    __shared__ int rows_g[128];
    const int tid = threadIdx.x;
    const int bm = blockIdx.x * 128;
    const int head = blockIdx.y;
    const uchar* WT = WT2f + (size_t)head * 65536;
    const float* bias = head ? b2b : b2a;

    // stage B: 256 rows x 32 chunks of 8B, rotated
    for (int idx = tid; idx < 256 * 32; idx += 512) {
        int nr = idx >> 5, seg = idx & 31;
        uint2 val = *(const uint2*)(WT + (size_t)nr * 256 + seg * 8);
        int slot = (seg + 2 * nr) & 31;
        *(uint2*)(Bs + nr * 256 + slot * 8) = val;
    }
    if (tid < 128) rows_g[tid] = batch[min(bm + tid, M - 1)];
    __syncthreads();

    const int warp = tid >> 6, lane = tid & 63;
    const int wr = warp >> 1, wc = warp & 1;    // 4 row-waves x 2 col-waves
    const int kgrp = lane >> 4;
    const int r0 = wr * 32 + (lane & 15);       // + m*16 (block-local row)
    const int c0 = wc * 128 + (lane & 15);      // + nf*16 (block-local col)

    f32x4 acc[2][8] = {};
    for (int ks = 0; ks < 8; ++ks) {
        const uchar* Aslab = z2f + ((size_t)(head * 8 + ks) * M) * 32;
        long a[2], b[8];
#pragma unroll
        for (int m = 0; m < 2; ++m) {
            int grow = bm + r0 + m * 16;
            a[m] = (grow < M)
                 ? *(const long*)(Aslab + (size_t)grow * 32 + kgrp * 8)
                 : 0L;
        }
#pragma unroll
        for (int nf = 0; nf < 8; ++nf) {
            int nr = c0 + nf * 16;
            int slot = (ks * 4 + kgrp + 2 * nr) & 31;
            b[nf] = *(const long*)(Bs + nr * 256 + slot * 8);
        }
#pragma unroll
        for (int nf = 0; nf < 8; ++nf)
#pragma unroll
            for (int m = 0; m < 2; ++m)
                acc[m][nf] = __builtin_amdgcn_mfma_f32_16x16x32_fp8_fp8(a[m], b[nf], acc[m][nf], 0, 0, 0);
    }

    // ---- fused pooling epilogue (wave's 32-row window spans <=2 graphs) ----
    const int rbw = wr * 32;
    const int g0 = rows_g[rbw];
    const int glast = rows_g[min(127, rbw + 31)];
    float s0[8] = {}, s1[8] = {};
#pragma unroll
    for (int m = 0; m < 2; ++m) {
#pragma unroll
        for (int r = 0; r < 4; ++r) {
            int lrow = rbw + m * 16 + (lane >> 4) * 4 + r;
            int grow = bm + lrow;
            if (grow < M) {
                bool in0 = (rows_g[lrow] == g0);
#pragma unroll
                for (int nf = 0; nf < 8; ++nf) {
                    float val = fmaxf(acc[m][nf][r] * 0.03125f + bias[c0 + nf * 16], 0.f);
                    if (in0) s0[nf] += val; else s1[nf] += val;
                }
            }
        }
    }
#pragma unroll
    for (int nf = 0; nf < 8; ++nf) {
        s0[nf] += __shfl_xor(s0[nf], 16, 64);
        s0[nf] += __shfl_xor(s0[nf], 32, 64);
        s1[nf] += __shfl_xor(s1[nf], 16, 64);
        s1[nf] += __shfl_xor(s1[nf], 32, 64);
    }
    if (kgrp == 0) {
#pragma unroll
        for (int nf = 0; nf < 8; ++nf) {
            int n = head * 256 + c0 + nf * 16;
            atomicAdd(&pooled[(size_t)g0 * 512 + n], s0[nf]);
            if (glast != g0) atomicAdd(&pooled[(size_t)glast * 512 + n], s1[nf]);
        }
    }
}

// final dot: 512 threads, head = t>>8, feature f = t&255
__global__ __launch_bounds__(512) void final_dot(
        const float* __restrict__ pooled, const int* __restrict__ sg,
        const int* __restrict__ eg, const float* __restrict__ action,
        const float* __restrict__ fcW1, const float* __restrict__ fcb1,
        const float* __restrict__ fcW2, const float* __restrict__ fcb2,
        float* __restrict__ out, int G) {
    int g = blockIdx.x, t = threadIdx.x;
    int head = t >> 8, f = t & 255;
    const float* fcW = head ? fcW2 : fcW1;
    float inv = 1.f / (float)(eg[g] - sg[g]);
    float p = pooled[g * 512 + t] * inv * fcW[f];
    if (f < ACTD) p += action[g * ACTD + f] * fcW[HID + f];
    for (int off = 32; off; off >>= 1) p += __shfl_down(p, off, 64);
    __shared__ float red[8];
    if ((t & 63) == 0) red[t >> 6] = p;
    __syncthreads();
    if (t == 0)   out[g]     = red[0] + red[1] + red[2] + red[3] + fcb1[0];
    if (t == 256) out[G + g] = red[4] + red[5] + red[6] + red[7] + fcb2[0];
}

// ---------------------------------------------------------------------------

extern "C" void kernel_launch(void* const* d_in, const int* in_sizes, int n_in,
                              void* d_out, int out_size, void* d_ws, size_t ws_size,
                              hipStream_t stream) {
    const float* x      = (const float*)d_in[0];
    const int*   ei     = (const int*)d_in[1];
    const int*   batch  = (const int*)d_in[2];
    const float* action = (const float*)d_in[3];
    const float* q1_W1  = (const float*)d_in[4];
    const float* q1_b1  = (const float*)d_in[5];
    const float* q1_W2  = (const float*)d_in[6];
    const float* q1_b2  = (const float*)d_in[7];
    const float* q1_fcW = (const float*)d_in[8];
    const float* q1_fcb = (const float*)d_in[9];
    const float* q2_W1  = (const float*)d_in[10];
    const float* q2_b1  = (const float*)d_in[11];
    const float* q2_W2  = (const float*)d_in[12];
    const float* q2_b2  = (const float*)d_in[13];
    const float* q2_fcW = (const float*)d_in[14];
    const float* q2_fcb = (const float*)d_in[15];

    const int N = in_sizes[2];
    const int E = in_sizes[1] / 2;
    const int G = in_sizes[3] / ACTD;
    const int* src = ei;
    const int* dst = ei + E;

    char* w = (char*)d_ws;
    size_t off = 0;
    auto take = [&](size_t bytes) -> void* {
        void* p = w + off;
        off = (off + bytes + 255) & ~(size_t)255;
        return p;
    };
    // cnt block: cnt[0..N-1], ticket=cnt[N]; pooled allocated immediately
    // after -> ONE zero_ws pass clears both.
    int*    cnt      = (int*)take((size_t)(N + 1) * 4);
    float*  pooled   = (float*)take((size_t)G * 512 * 4);
    int*    row_ptr  = (int*)take((size_t)N * 4);
    int*    row_end  = (int*)take((size_t)N * 4);
    float*  dis      = (float*)take((size_t)N * 4);
    int*    rank     = (int*)take((size_t)E * 4);
    int*    col_idx  = (int*)take((size_t)E * 4);
    int*    sg       = (int*)take((size_t)G * 4);
    int*    eg       = (int*)take((size_t)G * 4);
    ushort* WT1      = (ushort*)take((size_t)512 * FEAT * 2);    // bf16 [512][128]
    uchar*  WT2f     = (uchar*)take((size_t)2 * HID * HID);      // fp8 [2][256][256]
    uchar*  xs       = (uchar*)take((size_t)N * FEAT);           // fp8
    ushort* z        = (ushort*)take((size_t)N * FEAT * 2);      // bf16
    uchar*  h1       = (uchar*)take((size_t)N * 512);            // fp8
    uchar*  z2f      = (uchar*)take((size_t)N * 512);            // fp8 [16][N][32]
    (void)ws_size;

    const int TB = 256;
    const int nb = (N + 255) / 256;
    size_t zlen = (size_t)((char*)pooled - (char*)cnt) + (size_t)G * 512 * 4;
    int n16 = (int)((zlen + 15) / 16);
    zero_ws<<<(n16 + TB - 1) / TB, TB, 0, stream>>>((uint4*)cnt, n16);

    int hb_grid = (max(E, N) + TB - 1) / TB;
    hist_bounds<<<hb_grid, TB, 0, stream>>>(dst, cnt, E, batch, sg, eg, rank, N);
    scan_one<<<nb, TB, 0, stream>>>(cnt, row_ptr, row_end, dis, cnt + N, N);

    int fptotal = E + N * (FEAT / 4) + 2 * FEAT * HID + 2 * HID * HID;
    fill_prep<<<(fptotal + TB - 1) / TB, TB, 0, stream>>>(
        src, dst, row_ptr, rank, col_idx, E,
        x, dis, xs, q1_W1, q2_W1, q1_W2, q2_W2, WT1, WT2f, N);

    int agg_grid = (N + 3) / 4;
    int gx128 = (N + 127) / 128;

    agg128<<<agg_grid, TB, 0, stream>>>(xs, dis, row_ptr, row_end, col_idx, z, N);
    gemm1_mfma<<<dim3(gx128, 2), 512, 0, stream>>>(z, WT1, q1_b1, q2_b1, dis, h1, N);
    agg512<<<agg_grid, TB, 0, stream>>>(h1, dis, row_ptr, row_end, col_idx, z2f, N);
    gemm2_pool<<<dim3(gx128, 2), 512, 0, stream>>>(z2f, WT2f, q1_b2, q2_b2, batch,
                                                   pooled, N);
    final_dot<<<G, 512, 0, stream>>>(pooled, sg, eg, action,
                                     q1_fcW, q1_fcb, q2_fcW, q2_fcb,
                                     (float*)d_out, G);
}